// Round 2
// baseline (5382.763 us; speedup 1.0000x reference)
//
#include <hip/hip_runtime.h>
#include <math.h>

#define HH 384
#define WW 384
#define HWSZ (HH*WW)   // 147456
#define BB 4

// ---- workspace layout (float offsets). TOTAL ws need: 16384 + 56,623,104
// floats = 226.6 MB (round-0's 679.5 MB likely exceeded ws_size -> fault).
static const size_t OFF_MISC = 0;        // 16384 floats
static const size_t OFF_A    = 16384;    // big region, 56,623,104 floats
// sequenced reuse of region A:
//   det:    f1_det (64ch b0, 9.44M fl) @A ; f2_det (128ch b0, 18.87M fl) @A+9.44M
//   branch: t1 (4b x 64ch, 37.75M fl) @A            (xb lives in d_out!)
//   qkv:    qkvp (4b x 96ch, 56.62M fl) @A          (t1 dead)
//   v:      dw(v) written into qkvp's ch0..31 slots (q,k consumed by stats)
//   z1:     e1 output in-place over v
// misc (float offsets):
static const size_t MISC_POOLED = 0;     // 256 floats
static const size_t MISC_PRED   = 1024;  // 1 int
static const size_t MISC_STATS  = 1056;  // 32*(16+4+4)=768 floats
static const size_t MISC_MB     = 2048;  // 4*32*32=4096 floats

__device__ __forceinline__ float waveSum(float v) {
#pragma unroll
    for (int off = 32; off > 0; off >>= 1) v += __shfl_down(v, off);
    return v;
}

__device__ __forceinline__ float gelu_exact(float v) {
    return 0.5f * v * (1.0f + erff(v * 0.70710678118654752f));
}

// ---------------------------------------------------------------------------
// Direct 3x3 conv, pad=1, bias+ReLU. Spatial tile 128x8, 4 px/thread, 8 cout
// per block-y. mode 0: write out. mode 1: fused global-avg-pool accumulate.
// gate=1: read *predp; return if 0; weights (wA,bA) if pred==1 else (wB,bB).
// ---------------------------------------------------------------------------
__global__ __launch_bounds__(256, 2) void conv3x3_kernel(
    const float* __restrict__ in, int Cin,
    const float* __restrict__ wA, const float* __restrict__ bA,
    const float* __restrict__ wB, const float* __restrict__ bB,
    const int* __restrict__ predp, int gate,
    float* __restrict__ out, int Cout,
    float* __restrict__ pool, int mode)
{
    const float* wsel = wA;
    const float* bsel = bA;
    if (gate) {
        int p = __builtin_amdgcn_readfirstlane(*predp);
        if (p == 0) return;
        if (p == 2) { wsel = wB; bsel = bB; }
    }

    __shared__ float s_in[8][10][132];   // 8 ci x (8+2) rows x (130 used)

    const int tid = threadIdx.x;
    const int tx = tid & 31;           // 0..31 -> 4 px each
    const int ty = tid >> 5;           // 0..7
    const int tilesX = WW / 128;       // 3
    const int tX = blockIdx.x % tilesX;
    const int tY = blockIdx.x / tilesX;
    const int x0 = tX * 128;
    const int y0 = tY * 8;
    const int co0 = blockIdx.y * 8;
    const int b = blockIdx.z;

    float acc[4][8];
#pragma unroll
    for (int p4 = 0; p4 < 4; ++p4)
#pragma unroll
        for (int co = 0; co < 8; ++co) acc[p4][co] = 0.f;

    const float* inb = in + (size_t)b * Cin * HWSZ;

    for (int ci0 = 0; ci0 < Cin; ci0 += 8) {
        for (int idx = tid; idx < 8 * 10 * 130; idx += 256) {
            int ci = idx / 1300;
            int r = idx % 1300;
            int iy = r / 130;
            int ix = r % 130;
            int gy = y0 + iy - 1;
            int gx = x0 + ix - 1;
            float v = 0.f;
            if ((unsigned)gy < (unsigned)HH && (unsigned)gx < (unsigned)WW)
                v = inb[(size_t)(ci0 + ci) * HWSZ + gy * WW + gx];
            s_in[ci][iy][ix] = v;
        }
        __syncthreads();

#pragma unroll
        for (int ci = 0; ci < 8; ++ci) {
#pragma unroll
            for (int dy = 0; dy < 3; ++dy) {
                const float* row = &s_in[ci][ty + dy][tx * 4];
                float iv0 = row[0], iv1 = row[1], iv2 = row[2];
                float iv3 = row[3], iv4 = row[4], iv5 = row[5];
                const float* wrow = wsel + ((size_t)co0 * Cin + (ci0 + ci)) * 9 + dy * 3;
                const int wstride = Cin * 9;
#pragma unroll
                for (int dx = 0; dx < 3; ++dx) {
                    float a0 = (dx == 0) ? iv0 : (dx == 1) ? iv1 : iv2;
                    float a1 = (dx == 0) ? iv1 : (dx == 1) ? iv2 : iv3;
                    float a2 = (dx == 0) ? iv2 : (dx == 1) ? iv3 : iv4;
                    float a3 = (dx == 0) ? iv3 : (dx == 1) ? iv4 : iv5;
#pragma unroll
                    for (int co = 0; co < 8; ++co) {
                        float wv = wrow[co * wstride + dx];   // wave-uniform -> s_load
                        acc[0][co] = fmaf(a0, wv, acc[0][co]);
                        acc[1][co] = fmaf(a1, wv, acc[1][co]);
                        acc[2][co] = fmaf(a2, wv, acc[2][co]);
                        acc[3][co] = fmaf(a3, wv, acc[3][co]);
                    }
                }
            }
        }
        __syncthreads();
    }

    if (mode == 0) {
        const int ox = x0 + tx * 4;
        const int oy = y0 + ty;
#pragma unroll
        for (int co = 0; co < 8; ++co) {
            float bv = bsel[co0 + co];
            float4 v;
            v.x = fmaxf(acc[0][co] + bv, 0.f);
            v.y = fmaxf(acc[1][co] + bv, 0.f);
            v.z = fmaxf(acc[2][co] + bv, 0.f);
            v.w = fmaxf(acc[3][co] + bv, 0.f);
            *(float4*)&out[(size_t)(b * Cout + co0 + co) * HWSZ + oy * WW + ox] = v;
        }
    } else {
#pragma unroll
        for (int co = 0; co < 8; ++co) {
            float bv = bsel[co0 + co];
            float s = fmaxf(acc[0][co] + bv, 0.f) + fmaxf(acc[1][co] + bv, 0.f)
                    + fmaxf(acc[2][co] + bv, 0.f) + fmaxf(acc[3][co] + bv, 0.f);
            s = waveSum(s);
            if ((tid & 63) == 0) atomicAdd(&pool[co0 + co], s);
        }
    }
}

// ---------------------------------------------------------------------------
__global__ void fc_argmax_kernel(const float* __restrict__ pooled,
                                 const float* __restrict__ fcw,
                                 const float* __restrict__ fcb,
                                 int* __restrict__ pred)
{
    int t = threadIdx.x;   // 256 threads = 256 channels
    float m = pooled[t] * (1.0f / (float)HWSZ);
    float p0 = m * fcw[t];
    float p1 = m * fcw[256 + t];
    float p2 = m * fcw[512 + t];
    p0 = waveSum(p0); p1 = waveSum(p1); p2 = waveSum(p2);
    __shared__ float rr[3][4];
    int wid = t >> 6, lane = t & 63;
    if (lane == 0) { rr[0][wid] = p0; rr[1][wid] = p1; rr[2][wid] = p2; }
    __syncthreads();
    if (t == 0) {
        float l0 = rr[0][0] + rr[0][1] + rr[0][2] + rr[0][3] + fcb[0];
        float l1 = rr[1][0] + rr[1][1] + rr[1][2] + rr[1][3] + fcb[1];
        float l2 = rr[2][0] + rr[2][1] + rr[2][2] + rr[2][3] + fcb[2];
        int best = 0; float bv = l0;
        if (l1 > bv) { best = 1; bv = l1; }
        if (l2 > bv) { best = 2; bv = l2; }
        *pred = best;
    }
}

// ---------------------------------------------------------------------------
// fused channels_first LayerNorm (C=32) + 1x1 conv 32->96
__global__ __launch_bounds__(256) void lnpw_kernel(
    const float* __restrict__ x, const float* __restrict__ xb,
    const int* __restrict__ predp,
    const float* __restrict__ lnw, const float* __restrict__ lnb,
    const float* __restrict__ pww,
    float* __restrict__ qkvp)
{
    int p = blockIdx.x * 256 + threadIdx.x;
    if (p >= BB * HWSZ) return;
    int pr = __builtin_amdgcn_readfirstlane(*predp);
    const float* src = (pr == 0) ? x : xb;
    int b = p / HWSZ, n = p % HWSZ;
    const float* sp = src + (size_t)b * 32 * HWSZ + n;
    float v[32];
    float mean = 0.f;
#pragma unroll
    for (int c = 0; c < 32; ++c) { v[c] = sp[(size_t)c * HWSZ]; mean += v[c]; }
    mean *= (1.f / 32.f);
    float var = 0.f;
#pragma unroll
    for (int c = 0; c < 32; ++c) { float d = v[c] - mean; var += d * d; }
    var *= (1.f / 32.f);
    float rstd = rsqrtf(var + 1e-6f);
#pragma unroll
    for (int c = 0; c < 32; ++c)
        v[c] = (v[c] - mean) * rstd * lnw[c] + lnb[c];

    float acc[96];
#pragma unroll
    for (int co = 0; co < 96; ++co) acc[co] = 0.f;
    for (int ci = 0; ci < 32; ++ci) {
        float va = v[ci];
#pragma unroll
        for (int co = 0; co < 96; ++co)
            acc[co] = fmaf(pww[co * 32 + ci], va, acc[co]);   // uniform -> s_load
    }
    float* op = qkvp + (size_t)b * 96 * HWSZ + n;
#pragma unroll
    for (int co = 0; co < 96; ++co) op[(size_t)co * HWSZ] = acc[co];
}

// ---------------------------------------------------------------------------
// q/k depthwise-3x3 computed on the fly + stats per (b,h):
// S[c][d]=sum q_c k_d (16), Qn[c]=sum q_c^2, Kn[d]=sum k_d^2
__global__ __launch_bounds__(256) void qkdwstats_kernel(
    const float* __restrict__ qkvp, const float* __restrict__ dww,
    float* __restrict__ stats)
{
    int bh = blockIdx.y;
    int b = bh >> 3, h = bh & 7;
    const float* qbase = qkvp + ((size_t)b * 96 + h * 4) * HWSZ;
    const float* kbase = qkvp + ((size_t)b * 96 + 32 + h * 4) * HWSZ;
    const float* wq = dww + (h * 4) * 9;        // uniform -> s_load
    const float* wk = dww + (32 + h * 4) * 9;
    float s[16], qn[4], kn[4];
#pragma unroll
    for (int i = 0; i < 16; ++i) s[i] = 0.f;
#pragma unroll
    for (int i = 0; i < 4; ++i) { qn[i] = 0.f; kn[i] = 0.f; }
    int base = blockIdx.x * 16384 + threadIdx.x;   // 9 chunks * 16384 = 147456
    for (int i = 0; i < 64; ++i) {
        int n = base + i * 256;
        int y = n / WW, x = n % WW;
        float q[4], k[4];
#pragma unroll
        for (int l = 0; l < 4; ++l) { q[l] = 0.f; k[l] = 0.f; }
#pragma unroll
        for (int dy = 0; dy < 3; ++dy) {
            int gy = y + dy - 1;
            if ((unsigned)gy >= (unsigned)HH) continue;
#pragma unroll
            for (int dx = 0; dx < 3; ++dx) {
                int gx = x + dx - 1;
                if ((unsigned)gx >= (unsigned)WW) continue;
                int off = gy * WW + gx;
                int wi = dy * 3 + dx;
#pragma unroll
                for (int l = 0; l < 4; ++l) {
                    q[l] = fmaf(qbase[(size_t)l * HWSZ + off], wq[l * 9 + wi], q[l]);
                    k[l] = fmaf(kbase[(size_t)l * HWSZ + off], wk[l * 9 + wi], k[l]);
                }
            }
        }
#pragma unroll
        for (int c = 0; c < 4; ++c) {
            qn[c] = fmaf(q[c], q[c], qn[c]);
            kn[c] = fmaf(k[c], k[c], kn[c]);
#pragma unroll
            for (int d = 0; d < 4; ++d)
                s[c * 4 + d] = fmaf(q[c], k[d], s[c * 4 + d]);
        }
    }
    float* st = stats + bh * 24;
    int lane = threadIdx.x & 63;
#pragma unroll
    for (int i = 0; i < 16; ++i) {
        float v = waveSum(s[i]);
        if (lane == 0) atomicAdd(&st[i], v);
    }
#pragma unroll
    for (int i = 0; i < 4; ++i) {
        float v = waveSum(qn[i]);
        if (lane == 0) atomicAdd(&st[16 + i], v);
        float u = waveSum(kn[i]);
        if (lane == 0) atomicAdd(&st[20 + i], u);
    }
}

// ---------------------------------------------------------------------------
// depthwise 3x3 on v channels: reads qkvp ch 64+c, writes into qkvp ch c slot
__global__ __launch_bounds__(256) void vdw_kernel(
    float* __restrict__ qkvp, const float* __restrict__ dww)
{
    size_t idx = (size_t)blockIdx.x * 256 + threadIdx.x;
    int n = (int)(idx % HWSZ);
    int bc = (int)(idx / HWSZ);
    int b = bc >> 5, c = bc & 31;          // uniform within block
    const float* ip = qkvp + ((size_t)b * 96 + 64 + c) * HWSZ;
    const float* wc = dww + (64 + c) * 9;
    int y = n / WW, x = n % WW;
    float s = 0.f;
#pragma unroll
    for (int dy = 0; dy < 3; ++dy) {
        int gy = y + dy - 1;
        if ((unsigned)gy >= (unsigned)HH) continue;
#pragma unroll
        for (int dx = 0; dx < 3; ++dx) {
            int gx = x + dx - 1;
            if ((unsigned)gx >= (unsigned)WW) continue;
            s = fmaf(ip[gy * WW + gx], wc[dy * 3 + dx], s);
        }
    }
    qkvp[((size_t)b * 96 + c) * HWSZ + n] = s;
}

// ---------------------------------------------------------------------------
// finalize attention (normalize, temperature, softmax) and build per-batch
// fused matrix Mb[b][co][j=4h+d] = sum_l proj_w[co][4h+l] * attn[b][h][l][d]
__global__ void attnmb_kernel(const float* __restrict__ stats,
                              const float* __restrict__ temp,
                              const float* __restrict__ projw,
                              float* __restrict__ Mb)
{
    __shared__ float attn_s[4][8][4][4];
    int t = threadIdx.x;
    if (t < 128) {
        int b = t >> 5;
        int h = (t >> 2) & 7;
        int c = t & 3;
        const float* st = stats + (b * 8 + h) * 24;
        float qn = fmaxf(sqrtf(st[16 + c]), 1e-12f);
        float tp = temp[h];
        float raw[4];
#pragma unroll
        for (int d = 0; d < 4; ++d) {
            float kn = fmaxf(sqrtf(st[20 + d]), 1e-12f);
            raw[d] = st[c * 4 + d] / (qn * kn) * tp;
        }
        float m = fmaxf(fmaxf(raw[0], raw[1]), fmaxf(raw[2], raw[3]));
        float e0 = expf(raw[0] - m), e1 = expf(raw[1] - m);
        float e2 = expf(raw[2] - m), e3 = expf(raw[3] - m);
        float inv = 1.f / (e0 + e1 + e2 + e3);
        attn_s[b][h][c][0] = e0 * inv;
        attn_s[b][h][c][1] = e1 * inv;
        attn_s[b][h][c][2] = e2 * inv;
        attn_s[b][h][c][3] = e3 * inv;
    }
    __syncthreads();
    for (int idx = t; idx < 4096; idx += 256) {
        int b = idx >> 10;
        int r = idx & 1023;
        int co = r >> 5;
        int j = r & 31;
        int h = j >> 2;
        int d = j & 3;
        float m = 0.f;
#pragma unroll
        for (int l = 0; l < 4; ++l)
            m = fmaf(projw[co * 32 + h * 4 + l], attn_s[b][h][l][d], m);
        Mb[idx] = m;
    }
}

// ---------------------------------------------------------------------------
// epilogue 1 (in place over v): y = Mb@v + x_resid ; z1 = gelu(ff1 @ y)
// v lives in qkvp channel slots 0..31 per batch; z1 written to same slots.
__global__ __launch_bounds__(256) void e1_kernel(
    float* __restrict__ qkvp, const float* __restrict__ x,
    const float* __restrict__ xb, const int* __restrict__ predp,
    const float* __restrict__ Mb, const float* __restrict__ ff1w)
{
    int p = blockIdx.x * 256 + threadIdx.x;
    if (p >= BB * HWSZ) return;
    int pr = __builtin_amdgcn_readfirstlane(*predp);
    const float* src = (pr == 0) ? x : xb;
    int b = p / HWSZ, n = p % HWSZ;
    float* vp = qkvp + (size_t)b * 96 * HWSZ + n;
    const float* Mbb = Mb + b * 1024;   // uniform per block
    float y[32];
#pragma unroll
    for (int c = 0; c < 32; ++c) y[c] = 0.f;
    for (int j = 0; j < 32; ++j) {
        float vj = vp[(size_t)j * HWSZ];
#pragma unroll
        for (int co = 0; co < 32; ++co)
            y[co] = fmaf(Mbb[co * 32 + j], vj, y[co]);
    }
    const float* xp = src + (size_t)b * 32 * HWSZ + n;
#pragma unroll
    for (int c = 0; c < 32; ++c) y[c] += xp[(size_t)c * HWSZ];
    for (int co = 0; co < 32; ++co) {
        float s = 0.f;
#pragma unroll
        for (int ci = 0; ci < 32; ++ci)
            s = fmaf(ff1w[co * 32 + ci], y[ci], s);
        vp[(size_t)co * HWSZ] = gelu_exact(s);
    }
}

// ---------------------------------------------------------------------------
// final depthwise 3x3 + exact gelu: z1 (stride-96 layout) -> d_out (stride-32)
__global__ __launch_bounds__(256) void fdw_kernel(
    const float* __restrict__ z1, const float* __restrict__ w,
    float* __restrict__ out)
{
    size_t idx = (size_t)blockIdx.x * 256 + threadIdx.x;
    int n = (int)(idx % HWSZ);
    int bc = (int)(idx / HWSZ);
    int b = bc >> 5, c = bc & 31;          // uniform within block
    const float* ip = z1 + ((size_t)b * 96 + c) * HWSZ;
    const float* wc = w + c * 9;
    int y = n / WW, x = n % WW;
    float s = 0.f;
#pragma unroll
    for (int dy = 0; dy < 3; ++dy) {
        int gy = y + dy - 1;
        if ((unsigned)gy >= (unsigned)HH) continue;
#pragma unroll
        for (int dx = 0; dx < 3; ++dx) {
            int gx = x + dx - 1;
            if ((unsigned)gx >= (unsigned)WW) continue;
            s = fmaf(ip[gy * WW + gx], wc[dy * 3 + dx], s);
        }
    }
    out[((size_t)b * 32 + c) * HWSZ + n] = gelu_exact(s);
}

// ---------------------------------------------------------------------------
extern "C" void kernel_launch(void* const* d_in, const int* in_sizes, int n_in,
                              void* d_out, int out_size, void* d_ws, size_t ws_size,
                              hipStream_t stream)
{
    (void)in_sizes; (void)n_in; (void)out_size; (void)ws_size;
    const float* x      = (const float*)d_in[0];
    const float* ln_w   = (const float*)d_in[1];
    const float* ln_b   = (const float*)d_in[2];
    const float* temp   = (const float*)d_in[3];
    const float* pw_w   = (const float*)d_in[4];
    const float* dw_w   = (const float*)d_in[5];
    const float* proj_w = (const float*)d_in[6];
    const float* ff1_w  = (const float*)d_in[7];
    const float* ffdw_w = (const float*)d_in[8];
    const float* det_w1 = (const float*)d_in[9];
    const float* det_b1 = (const float*)d_in[10];
    const float* det_w2 = (const float*)d_in[11];
    const float* det_b2 = (const float*)d_in[12];
    const float* det_w3 = (const float*)d_in[13];
    const float* det_b3 = (const float*)d_in[14];
    const float* fc_w   = (const float*)d_in[15];
    const float* fc_b   = (const float*)d_in[16];
    const float* hvi_w1 = (const float*)d_in[17];
    const float* hvi_b1 = (const float*)d_in[18];
    const float* hvi_w2 = (const float*)d_in[19];
    const float* hvi_b2 = (const float*)d_in[20];
    const float* ycc_w1 = (const float*)d_in[21];
    const float* ycc_b1 = (const float*)d_in[22];
    const float* ycc_w2 = (const float*)d_in[23];
    const float* ycc_b2 = (const float*)d_in[24];

    float* ws     = (float*)d_ws;
    float* misc   = ws + OFF_MISC;
    float* A      = ws + OFF_A;
    float* f1_det = A;                      //  9,437,184 fl (b0, 64ch)
    float* f2_det = A + 9437184;            // 18,874,368 fl (b0, 128ch)
    float* t1     = A;                      // 37,748,736 fl (4b, 64ch)
    float* qkvp   = A;                      // 56,623,104 fl (4b, 96ch)
    float* xb     = (float*)d_out;          // branch output lives in d_out
    float* pooled = misc + MISC_POOLED;
    int*   pred   = (int*)(misc + MISC_PRED);
    float* stats  = misc + MISC_STATS;
    float* Mb     = misc + MISC_MB;
    float* out    = (float*)d_out;

    // zero pooled sums + pred + stats accumulators (ws is poisoned each call)
    hipMemsetAsync(misc, 0, 2048 * sizeof(float), stream);

    dim3 blk(256);
    // ---- detector, batch 0 only (only argmax(logits[0]) is consumed) ----
    conv3x3_kernel<<<dim3(144,  8, 1), blk, 0, stream>>>(x, 32, det_w1, det_b1, nullptr, nullptr, nullptr, 0, f1_det, 64, nullptr, 0);
    conv3x3_kernel<<<dim3(144, 16, 1), blk, 0, stream>>>(f1_det, 64, det_w2, det_b2, nullptr, nullptr, nullptr, 0, f2_det, 128, nullptr, 0);
    conv3x3_kernel<<<dim3(144, 32, 1), blk, 0, stream>>>(f2_det, 128, det_w3, det_b3, nullptr, nullptr, nullptr, 0, nullptr, 256, pooled, 1);
    fc_argmax_kernel<<<1, 256, 0, stream>>>(pooled, fc_w, fc_b, pred);

    // ---- gated color-space branch (all batches); xb := d_out ----
    conv3x3_kernel<<<dim3(144, 8, BB), blk, 0, stream>>>(x, 32, hvi_w1, hvi_b1, ycc_w1, ycc_b1, pred, 1, t1, 64, nullptr, 0);
    conv3x3_kernel<<<dim3(144, 4, BB), blk, 0, stream>>>(t1, 64, hvi_w2, hvi_b2, ycc_w2, ycc_b2, pred, 1, xb, 32, nullptr, 0);

    // ---- fused LN + pw(1x1) -> qkvp (overwrites t1, dead) ----
    lnpw_kernel<<<2304, blk, 0, stream>>>(x, xb, pred, ln_w, ln_b, pw_w, qkvp);

    // ---- q/k dw-on-the-fly + stats; then v dw into q-channel slots ----
    qkdwstats_kernel<<<dim3(9, 32), blk, 0, stream>>>(qkvp, dw_w, stats);
    vdw_kernel<<<73728, blk, 0, stream>>>(qkvp, dw_w);
    attnmb_kernel<<<1, 256, 0, stream>>>(stats, temp, proj_w, Mb);

    // ---- epilogue: attn-out + residual + ff1 + gelu (in place), final dw ----
    e1_kernel<<<2304, blk, 0, stream>>>(qkvp, x, xb, pred, Mb, ff1_w);
    fdw_kernel<<<73728, blk, 0, stream>>>(qkvp, ffdw_w, out);
}

// Round 3
// 3106.972 us; speedup vs baseline: 1.7325x; 1.7325x over previous
//
#include <hip/hip_runtime.h>
#include <hip/hip_bf16.h>
#include <math.h>

#define HH 384
#define WW 384
#define HWSZ (HH*WW)   // 147456
#define BB 4

typedef __attribute__((ext_vector_type(8))) short short8;
typedef __attribute__((ext_vector_type(4))) float f32x4;

// ---- workspace layout (float offsets). TOTAL: 16384 + 56,623,104 fl = 226.6 MB
static const size_t OFF_MISC = 0;        // 16384 floats
static const size_t OFF_A    = 16384;    // big region, 56,623,104 floats
// region-A sequenced reuse (float offsets within A):
//   det phase:  x0 bf16   @0          (2,359,296 fl)
//               f1 bf16   @2,359,296  (4,718,592 fl)
//               f2 bf16   @7,077,888  (9,437,184 fl)
//               d3out bf16@16,515,072 (18,874,368 fl)  ends 35,389,440
//               W' bf16   @56,423,104 (193,536 fl)     ends 56,616,640
//   branch:     t1 fp32   @0          (37,748,736 fl)  (xb lives in d_out)
//   qkv:        qkvp fp32 @0          (56,623,104 fl)
// misc (float offsets):
static const size_t MISC_POOLED = 0;     // 256 floats
static const size_t MISC_PRED   = 1024;  // 1 int
static const size_t MISC_STATS  = 1056;  // 768 floats
static const size_t MISC_MB     = 2048;  // 4096 floats

__device__ __forceinline__ float waveSum(float v) {
#pragma unroll
    for (int off = 32; off > 0; off >>= 1) v += __shfl_down(v, off);
    return v;
}

__device__ __forceinline__ float gelu_exact(float v) {
    return 0.5f * v * (1.0f + erff(v * 0.70710678118654752f));
}

__device__ __forceinline__ unsigned short f2bf(float f) {
    __hip_bfloat16 h = __float2bfloat16(f);
    return *(unsigned short*)&h;
}
__device__ __forceinline__ float bf2f(unsigned short u) {
    unsigned int b = ((unsigned int)u) << 16;
    return __uint_as_float(b);
}

// ===========================================================================
// DETECTOR PATH (bf16 MFMA) — only argmax(logits[0]) is consumed, so bf16
// precision is more than sufficient.
// ===========================================================================

// x batch0: NCHW fp32 -> NHWC bf16
__global__ __launch_bounds__(256) void xcvt_kernel(
    const float* __restrict__ x, unsigned short* __restrict__ x0)
{
    int px = blockIdx.x * 256 + threadIdx.x;
    if (px >= HWSZ) return;
    unsigned short u[32];
#pragma unroll
    for (int c = 0; c < 32; ++c) u[c] = f2bf(x[(size_t)c * HWSZ + px]);
    uint4* dst = (uint4*)(x0 + (size_t)px * 32);
#pragma unroll
    for (int g = 0; g < 4; ++g) {
        uint4 v;
        v.x = (unsigned)u[g*8+0] | ((unsigned)u[g*8+1] << 16);
        v.y = (unsigned)u[g*8+2] | ((unsigned)u[g*8+3] << 16);
        v.z = (unsigned)u[g*8+4] | ((unsigned)u[g*8+5] << 16);
        v.w = (unsigned)u[g*8+6] | ((unsigned)u[g*8+7] << 16);
        dst[g] = v;
    }
}

// weights OIHW fp32 -> [co][e=dy*3+dx][ci] bf16
__global__ __launch_bounds__(256) void wcvt_kernel(
    const float* __restrict__ w, unsigned short* __restrict__ wp,
    int Cin, int total)
{
    int t = blockIdx.x * 256 + threadIdx.x;
    if (t >= total) return;
    int nine_cin = 9 * Cin;
    int co = t / nine_cin;
    int r = t - co * nine_cin;
    int e = r / Cin;
    int ci = r - e * Cin;
    wp[t] = f2bf(w[(size_t)co * nine_cin + ci * 9 + e]);
}

// implicit-GEMM 3x3 conv, pad=1, bias+ReLU. NHWC bf16 in/out.
// Block: 256 thr = 4 waves; tile 64 px x 64 co; wave = 16 px x 64 co
// (4 accumulators of mfma_f32_16x16x32_bf16).
template<int CIN>
__global__ __launch_bounds__(256) void mfma_conv_kernel(
    const unsigned short* __restrict__ in,
    const unsigned short* __restrict__ wp,
    const float* __restrict__ bias,
    unsigned short* __restrict__ out, int Cout)
{
    const int lane = threadIdx.x & 63;
    const int wave = threadIdx.x >> 6;
    const int nl = lane & 15;     // n (pixel) for B/D, m (co) for A
    const int quad = lane >> 4;   // k-group
    const int px = blockIdx.x * 64 + wave * 16 + nl;
    const int xx0 = px % WW;
    const int yy0 = px / WW;
    const int co0 = blockIdx.y * 64;

    f32x4 acc[4];
#pragma unroll
    for (int t = 0; t < 4; ++t) acc[t] = (f32x4){0.f, 0.f, 0.f, 0.f};

    const short8 zero8 = {0,0,0,0,0,0,0,0};
    const size_t wco_base0 = (size_t)(co0 + nl) * (9 * CIN) + quad * 8;

    for (int e = 0; e < 9; ++e) {
        const int dy = e / 3 - 1;
        const int dx = e % 3 - 1;
        const int xs = xx0 + dx;
        const int ys = yy0 + dy;
        const bool valid = ((unsigned)xs < (unsigned)WW) && ((unsigned)ys < (unsigned)HH);
        const unsigned short* bptr = in + (size_t)(ys * WW + xs) * CIN + quad * 8;
        const unsigned short* aptr0 = wp + wco_base0 + e * CIN;
#pragma unroll
        for (int ci0 = 0; ci0 < CIN; ci0 += 32) {
            short8 bfrag = valid ? *(const short8*)(bptr + ci0) : zero8;
#pragma unroll
            for (int t = 0; t < 4; ++t) {
                short8 afrag = *(const short8*)(aptr0 + (size_t)t * 16 * 9 * CIN + ci0);
                acc[t] = __builtin_amdgcn_mfma_f32_16x16x32_bf16(afrag, bfrag, acc[t], 0, 0, 0);
            }
        }
    }

    // D layout: col(px)=lane&15, row(co)=quad*4+reg -> 4 consecutive co per lane
    unsigned short* op = out + (size_t)px * Cout + co0;
#pragma unroll
    for (int t = 0; t < 4; ++t) {
        int cbase = t * 16 + quad * 4;
        ushort4 v;
        float r0 = fmaxf(acc[t][0] + bias[co0 + cbase + 0], 0.f);
        float r1 = fmaxf(acc[t][1] + bias[co0 + cbase + 1], 0.f);
        float r2 = fmaxf(acc[t][2] + bias[co0 + cbase + 2], 0.f);
        float r3 = fmaxf(acc[t][3] + bias[co0 + cbase + 3], 0.f);
        v.x = f2bf(r0); v.y = f2bf(r1); v.z = f2bf(r2); v.w = f2bf(r3);
        *(ushort4*)(op + cbase) = v;
    }
}

// global-average-pool sums over det3 output [HW][256] bf16 -> pooled[256] (sums)
__global__ __launch_bounds__(256) void pool_kernel(
    const unsigned short* __restrict__ d3, float* __restrict__ pooled)
{
    __shared__ float s_pool[256];
    int t = threadIdx.x;
    s_pool[t] = 0.f;
    __syncthreads();
    int co8 = (t & 31) * 8;
    int pxg = t >> 5;                 // 0..7
    float sums[8];
#pragma unroll
    for (int j = 0; j < 8; ++j) sums[j] = 0.f;
    int base = blockIdx.x * 2304 + pxg;
    for (int i = 0; i < 288; ++i) {
        int px = base + i * 8;
        const uint4* p = (const uint4*)(d3 + (size_t)px * 256 + co8);
        uint4 v = *p;
        unsigned int w[4] = {v.x, v.y, v.z, v.w};
#pragma unroll
        for (int g = 0; g < 4; ++g) {
            sums[g*2+0] += bf2f((unsigned short)(w[g] & 0xFFFF));
            sums[g*2+1] += bf2f((unsigned short)(w[g] >> 16));
        }
    }
#pragma unroll
    for (int j = 0; j < 8; ++j) atomicAdd(&s_pool[co8 + j], sums[j]);
    __syncthreads();
    atomicAdd(&pooled[t], s_pool[t]);
}

// ---------------------------------------------------------------------------
__global__ void fc_argmax_kernel(const float* __restrict__ pooled,
                                 const float* __restrict__ fcw,
                                 const float* __restrict__ fcb,
                                 int* __restrict__ pred)
{
    int t = threadIdx.x;   // 256 threads = 256 channels
    float m = pooled[t] * (1.0f / (float)HWSZ);
    float p0 = m * fcw[t];
    float p1 = m * fcw[256 + t];
    float p2 = m * fcw[512 + t];
    p0 = waveSum(p0); p1 = waveSum(p1); p2 = waveSum(p2);
    __shared__ float rr[3][4];
    int wid = t >> 6, lane = t & 63;
    if (lane == 0) { rr[0][wid] = p0; rr[1][wid] = p1; rr[2][wid] = p2; }
    __syncthreads();
    if (t == 0) {
        float l0 = rr[0][0] + rr[0][1] + rr[0][2] + rr[0][3] + fcb[0];
        float l1 = rr[1][0] + rr[1][1] + rr[1][2] + rr[1][3] + fcb[1];
        float l2 = rr[2][0] + rr[2][1] + rr[2][2] + rr[2][3] + fcb[2];
        int best = 0; float bv = l0;
        if (l1 > bv) { best = 1; bv = l1; }
        if (l2 > bv) { best = 2; bv = l2; }
        *pred = best;
    }
}

// ===========================================================================
// BRANCH convs — exact fp32 path (numerically relevant, but gated: zero cost
// when pred==0).
// ===========================================================================
__global__ __launch_bounds__(256, 2) void conv3x3_kernel(
    const float* __restrict__ in, int Cin,
    const float* __restrict__ wA, const float* __restrict__ bA,
    const float* __restrict__ wB, const float* __restrict__ bB,
    const int* __restrict__ predp,
    float* __restrict__ out, int Cout)
{
    const float* wsel = wA;
    const float* bsel = bA;
    {
        int p = __builtin_amdgcn_readfirstlane(*predp);
        if (p == 0) return;
        if (p == 2) { wsel = wB; bsel = bB; }
    }

    __shared__ float s_in[8][10][132];

    const int tid = threadIdx.x;
    const int tx = tid & 31;
    const int ty = tid >> 5;
    const int tilesX = WW / 128;
    const int tX = blockIdx.x % tilesX;
    const int tY = blockIdx.x / tilesX;
    const int x0 = tX * 128;
    const int y0 = tY * 8;
    const int co0 = blockIdx.y * 8;
    const int b = blockIdx.z;

    float acc[4][8];
#pragma unroll
    for (int p4 = 0; p4 < 4; ++p4)
#pragma unroll
        for (int co = 0; co < 8; ++co) acc[p4][co] = 0.f;

    const float* inb = in + (size_t)b * Cin * HWSZ;

    for (int ci0 = 0; ci0 < Cin; ci0 += 8) {
        for (int idx = tid; idx < 8 * 10 * 130; idx += 256) {
            int ci = idx / 1300;
            int r = idx % 1300;
            int iy = r / 130;
            int ix = r % 130;
            int gy = y0 + iy - 1;
            int gx = x0 + ix - 1;
            float v = 0.f;
            if ((unsigned)gy < (unsigned)HH && (unsigned)gx < (unsigned)WW)
                v = inb[(size_t)(ci0 + ci) * HWSZ + gy * WW + gx];
            s_in[ci][iy][ix] = v;
        }
        __syncthreads();

#pragma unroll
        for (int ci = 0; ci < 8; ++ci) {
#pragma unroll
            for (int dy = 0; dy < 3; ++dy) {
                const float* row = &s_in[ci][ty + dy][tx * 4];
                float iv0 = row[0], iv1 = row[1], iv2 = row[2];
                float iv3 = row[3], iv4 = row[4], iv5 = row[5];
                const float* wrow = wsel + ((size_t)co0 * Cin + (ci0 + ci)) * 9 + dy * 3;
                const int wstride = Cin * 9;
#pragma unroll
                for (int dx = 0; dx < 3; ++dx) {
                    float a0 = (dx == 0) ? iv0 : (dx == 1) ? iv1 : iv2;
                    float a1 = (dx == 0) ? iv1 : (dx == 1) ? iv2 : iv3;
                    float a2 = (dx == 0) ? iv2 : (dx == 1) ? iv3 : iv4;
                    float a3 = (dx == 0) ? iv3 : (dx == 1) ? iv4 : iv5;
#pragma unroll
                    for (int co = 0; co < 8; ++co) {
                        float wv = wrow[co * wstride + dx];
                        acc[0][co] = fmaf(a0, wv, acc[0][co]);
                        acc[1][co] = fmaf(a1, wv, acc[1][co]);
                        acc[2][co] = fmaf(a2, wv, acc[2][co]);
                        acc[3][co] = fmaf(a3, wv, acc[3][co]);
                    }
                }
            }
        }
        __syncthreads();
    }

    const int ox = x0 + tx * 4;
    const int oy = y0 + ty;
#pragma unroll
    for (int co = 0; co < 8; ++co) {
        float bv = bsel[co0 + co];
        float4 v;
        v.x = fmaxf(acc[0][co] + bv, 0.f);
        v.y = fmaxf(acc[1][co] + bv, 0.f);
        v.z = fmaxf(acc[2][co] + bv, 0.f);
        v.w = fmaxf(acc[3][co] + bv, 0.f);
        *(float4*)&out[(size_t)(b * Cout + co0 + co) * HWSZ + oy * WW + ox] = v;
    }
}

// ===========================================================================
// NUMERIC CHAIN — fp32 (unchanged from round 2)
// ===========================================================================
__global__ __launch_bounds__(256) void lnpw_kernel(
    const float* __restrict__ x, const float* __restrict__ xb,
    const int* __restrict__ predp,
    const float* __restrict__ lnw, const float* __restrict__ lnb,
    const float* __restrict__ pww,
    float* __restrict__ qkvp)
{
    int p = blockIdx.x * 256 + threadIdx.x;
    if (p >= BB * HWSZ) return;
    int pr = __builtin_amdgcn_readfirstlane(*predp);
    const float* src = (pr == 0) ? x : xb;
    int b = p / HWSZ, n = p % HWSZ;
    const float* sp = src + (size_t)b * 32 * HWSZ + n;
    float v[32];
    float mean = 0.f;
#pragma unroll
    for (int c = 0; c < 32; ++c) { v[c] = sp[(size_t)c * HWSZ]; mean += v[c]; }
    mean *= (1.f / 32.f);
    float var = 0.f;
#pragma unroll
    for (int c = 0; c < 32; ++c) { float d = v[c] - mean; var += d * d; }
    var *= (1.f / 32.f);
    float rstd = rsqrtf(var + 1e-6f);
#pragma unroll
    for (int c = 0; c < 32; ++c)
        v[c] = (v[c] - mean) * rstd * lnw[c] + lnb[c];

    float acc[96];
#pragma unroll
    for (int co = 0; co < 96; ++co) acc[co] = 0.f;
    for (int ci = 0; ci < 32; ++ci) {
        float va = v[ci];
#pragma unroll
        for (int co = 0; co < 96; ++co)
            acc[co] = fmaf(pww[co * 32 + ci], va, acc[co]);
    }
    float* op = qkvp + (size_t)b * 96 * HWSZ + n;
#pragma unroll
    for (int co = 0; co < 96; ++co) op[(size_t)co * HWSZ] = acc[co];
}

__global__ __launch_bounds__(256) void qkdwstats_kernel(
    const float* __restrict__ qkvp, const float* __restrict__ dww,
    float* __restrict__ stats)
{
    int bh = blockIdx.y;
    int b = bh >> 3, h = bh & 7;
    const float* qbase = qkvp + ((size_t)b * 96 + h * 4) * HWSZ;
    const float* kbase = qkvp + ((size_t)b * 96 + 32 + h * 4) * HWSZ;
    const float* wq = dww + (h * 4) * 9;
    const float* wk = dww + (32 + h * 4) * 9;
    float s[16], qn[4], kn[4];
#pragma unroll
    for (int i = 0; i < 16; ++i) s[i] = 0.f;
#pragma unroll
    for (int i = 0; i < 4; ++i) { qn[i] = 0.f; kn[i] = 0.f; }
    int base = blockIdx.x * 16384 + threadIdx.x;
    for (int i = 0; i < 64; ++i) {
        int n = base + i * 256;
        int y = n / WW, x = n % WW;
        float q[4], k[4];
#pragma unroll
        for (int l = 0; l < 4; ++l) { q[l] = 0.f; k[l] = 0.f; }
#pragma unroll
        for (int dy = 0; dy < 3; ++dy) {
            int gy = y + dy - 1;
            if ((unsigned)gy >= (unsigned)HH) continue;
#pragma unroll
            for (int dx = 0; dx < 3; ++dx) {
                int gx = x + dx - 1;
                if ((unsigned)gx >= (unsigned)WW) continue;
                int off = gy * WW + gx;
                int wi = dy * 3 + dx;
#pragma unroll
                for (int l = 0; l < 4; ++l) {
                    q[l] = fmaf(qbase[(size_t)l * HWSZ + off], wq[l * 9 + wi], q[l]);
                    k[l] = fmaf(kbase[(size_t)l * HWSZ + off], wk[l * 9 + wi], k[l]);
                }
            }
        }
#pragma unroll
        for (int c = 0; c < 4; ++c) {
            qn[c] = fmaf(q[c], q[c], qn[c]);
            kn[c] = fmaf(k[c], k[c], kn[c]);
#pragma unroll
            for (int d = 0; d < 4; ++d)
                s[c * 4 + d] = fmaf(q[c], k[d], s[c * 4 + d]);
        }
    }
    float* st = stats + bh * 24;
    int lane = threadIdx.x & 63;
#pragma unroll
    for (int i = 0; i < 16; ++i) {
        float v = waveSum(s[i]);
        if (lane == 0) atomicAdd(&st[i], v);
    }
#pragma unroll
    for (int i = 0; i < 4; ++i) {
        float v = waveSum(qn[i]);
        if (lane == 0) atomicAdd(&st[16 + i], v);
        float u = waveSum(kn[i]);
        if (lane == 0) atomicAdd(&st[20 + i], u);
    }
}

__global__ __launch_bounds__(256) void vdw_kernel(
    float* __restrict__ qkvp, const float* __restrict__ dww)
{
    size_t idx = (size_t)blockIdx.x * 256 + threadIdx.x;
    int n = (int)(idx % HWSZ);
    int bc = (int)(idx / HWSZ);
    int b = bc >> 5, c = bc & 31;
    const float* ip = qkvp + ((size_t)b * 96 + 64 + c) * HWSZ;
    const float* wc = dww + (64 + c) * 9;
    int y = n / WW, x = n % WW;
    float s = 0.f;
#pragma unroll
    for (int dy = 0; dy < 3; ++dy) {
        int gy = y + dy - 1;
        if ((unsigned)gy >= (unsigned)HH) continue;
#pragma unroll
        for (int dx = 0; dx < 3; ++dx) {
            int gx = x + dx - 1;
            if ((unsigned)gx >= (unsigned)WW) continue;
            s = fmaf(ip[gy * WW + gx], wc[dy * 3 + dx], s);
        }
    }
    qkvp[((size_t)b * 96 + c) * HWSZ + n] = s;
}

__global__ void attnmb_kernel(const float* __restrict__ stats,
                              const float* __restrict__ temp,
                              const float* __restrict__ projw,
                              float* __restrict__ Mb)
{
    __shared__ float attn_s[4][8][4][4];
    int t = threadIdx.x;
    if (t < 128) {
        int b = t >> 5;
        int h = (t >> 2) & 7;
        int c = t & 3;
        const float* st = stats + (b * 8 + h) * 24;
        float qn = fmaxf(sqrtf(st[16 + c]), 1e-12f);
        float tp = temp[h];
        float raw[4];
#pragma unroll
        for (int d = 0; d < 4; ++d) {
            float kn = fmaxf(sqrtf(st[20 + d]), 1e-12f);
            raw[d] = st[c * 4 + d] / (qn * kn) * tp;
        }
        float m = fmaxf(fmaxf(raw[0], raw[1]), fmaxf(raw[2], raw[3]));
        float e0 = expf(raw[0] - m), e1 = expf(raw[1] - m);
        float e2 = expf(raw[2] - m), e3 = expf(raw[3] - m);
        float inv = 1.f / (e0 + e1 + e2 + e3);
        attn_s[b][h][c][0] = e0 * inv;
        attn_s[b][h][c][1] = e1 * inv;
        attn_s[b][h][c][2] = e2 * inv;
        attn_s[b][h][c][3] = e3 * inv;
    }
    __syncthreads();
    for (int idx = t; idx < 4096; idx += 256) {
        int b = idx >> 10;
        int r = idx & 1023;
        int co = r >> 5;
        int j = r & 31;
        int h = j >> 2;
        int d = j & 3;
        float m = 0.f;
#pragma unroll
        for (int l = 0; l < 4; ++l)
            m = fmaf(projw[co * 32 + h * 4 + l], attn_s[b][h][l][d], m);
        Mb[idx] = m;
    }
}

__global__ __launch_bounds__(256) void e1_kernel(
    float* __restrict__ qkvp, const float* __restrict__ x,
    const float* __restrict__ xb, const int* __restrict__ predp,
    const float* __restrict__ Mb, const float* __restrict__ ff1w)
{
    int p = blockIdx.x * 256 + threadIdx.x;
    if (p >= BB * HWSZ) return;
    int pr = __builtin_amdgcn_readfirstlane(*predp);
    const float* src = (pr == 0) ? x : xb;
    int b = p / HWSZ, n = p % HWSZ;
    float* vp = qkvp + (size_t)b * 96 * HWSZ + n;
    const float* Mbb = Mb + b * 1024;
    float y[32];
#pragma unroll
    for (int c = 0; c < 32; ++c) y[c] = 0.f;
    for (int j = 0; j < 32; ++j) {
        float vj = vp[(size_t)j * HWSZ];
#pragma unroll
        for (int co = 0; co < 32; ++co)
            y[co] = fmaf(Mbb[co * 32 + j], vj, y[co]);
    }
    const float* xp = src + (size_t)b * 32 * HWSZ + n;
#pragma unroll
    for (int c = 0; c < 32; ++c) y[c] += xp[(size_t)c * HWSZ];
    for (int co = 0; co < 32; ++co) {
        float s = 0.f;
#pragma unroll
        for (int ci = 0; ci < 32; ++ci)
            s = fmaf(ff1w[co * 32 + ci], y[ci], s);
        vp[(size_t)co * HWSZ] = gelu_exact(s);
    }
}

__global__ __launch_bounds__(256) void fdw_kernel(
    const float* __restrict__ z1, const float* __restrict__ w,
    float* __restrict__ out)
{
    size_t idx = (size_t)blockIdx.x * 256 + threadIdx.x;
    int n = (int)(idx % HWSZ);
    int bc = (int)(idx / HWSZ);
    int b = bc >> 5, c = bc & 31;
    const float* ip = z1 + ((size_t)b * 96 + c) * HWSZ;
    const float* wc = w + c * 9;
    int y = n / WW, x = n % WW;
    float s = 0.f;
#pragma unroll
    for (int dy = 0; dy < 3; ++dy) {
        int gy = y + dy - 1;
        if ((unsigned)gy >= (unsigned)HH) continue;
#pragma unroll
        for (int dx = 0; dx < 3; ++dx) {
            int gx = x + dx - 1;
            if ((unsigned)gx >= (unsigned)WW) continue;
            s = fmaf(ip[gy * WW + gx], wc[dy * 3 + dx], s);
        }
    }
    out[((size_t)b * 32 + c) * HWSZ + n] = gelu_exact(s);
}

// ---------------------------------------------------------------------------
extern "C" void kernel_launch(void* const* d_in, const int* in_sizes, int n_in,
                              void* d_out, int out_size, void* d_ws, size_t ws_size,
                              hipStream_t stream)
{
    (void)in_sizes; (void)n_in; (void)out_size; (void)ws_size;
    const float* x      = (const float*)d_in[0];
    const float* ln_w   = (const float*)d_in[1];
    const float* ln_b   = (const float*)d_in[2];
    const float* temp   = (const float*)d_in[3];
    const float* pw_w   = (const float*)d_in[4];
    const float* dw_w   = (const float*)d_in[5];
    const float* proj_w = (const float*)d_in[6];
    const float* ff1_w  = (const float*)d_in[7];
    const float* ffdw_w = (const float*)d_in[8];
    const float* det_w1 = (const float*)d_in[9];
    const float* det_b1 = (const float*)d_in[10];
    const float* det_w2 = (const float*)d_in[11];
    const float* det_b2 = (const float*)d_in[12];
    const float* det_w3 = (const float*)d_in[13];
    const float* det_b3 = (const float*)d_in[14];
    const float* fc_w   = (const float*)d_in[15];
    const float* fc_b   = (const float*)d_in[16];
    const float* hvi_w1 = (const float*)d_in[17];
    const float* hvi_b1 = (const float*)d_in[18];
    const float* hvi_w2 = (const float*)d_in[19];
    const float* hvi_b2 = (const float*)d_in[20];
    const float* ycc_w1 = (const float*)d_in[21];
    const float* ycc_b1 = (const float*)d_in[22];
    const float* ycc_w2 = (const float*)d_in[23];
    const float* ycc_b2 = (const float*)d_in[24];

    float* ws     = (float*)d_ws;
    float* misc   = ws + OFF_MISC;
    float* A      = ws + OFF_A;
    // det phase (bf16 buffers carved from A)
    unsigned short* x0bf  = (unsigned short*)A;                      // @0
    unsigned short* f1bf  = (unsigned short*)(A + 2359296);
    unsigned short* f2bf  = (unsigned short*)(A + 7077888);
    unsigned short* d3out = (unsigned short*)(A + 16515072);
    unsigned short* w1p   = (unsigned short*)(A + 56423104);
    unsigned short* w2p   = (unsigned short*)(A + 56432320);
    unsigned short* w3p   = (unsigned short*)(A + 56469184);
    // later phases
    float* t1     = A;                      // 37,748,736 fl (4b, 64ch)
    float* qkvp   = A;                      // 56,623,104 fl (4b, 96ch)
    float* xb     = (float*)d_out;          // branch output lives in d_out
    float* pooled = misc + MISC_POOLED;
    int*   pred   = (int*)(misc + MISC_PRED);
    float* stats  = misc + MISC_STATS;
    float* Mb     = misc + MISC_MB;
    float* out    = (float*)d_out;

    hipMemsetAsync(misc, 0, 2048 * sizeof(float), stream);

    dim3 blk(256);
    // ---- weight + input conversion for MFMA detector ----
    wcvt_kernel<<<(18432 + 255) / 256, blk, 0, stream>>>(det_w1, w1p, 32, 18432);
    wcvt_kernel<<<(73728 + 255) / 256, blk, 0, stream>>>(det_w2, w2p, 64, 73728);
    wcvt_kernel<<<(294912 + 255) / 256, blk, 0, stream>>>(det_w3, w3p, 128, 294912);
    xcvt_kernel<<<576, blk, 0, stream>>>(x, x0bf);

    // ---- detector (batch 0 only; feeds argmax -> bf16 MFMA) ----
    mfma_conv_kernel<32><<<dim3(2304, 1), blk, 0, stream>>>(x0bf, w1p, det_b1, f1bf, 64);
    mfma_conv_kernel<64><<<dim3(2304, 2), blk, 0, stream>>>(f1bf, w2p, det_b2, f2bf, 128);
    mfma_conv_kernel<128><<<dim3(2304, 4), blk, 0, stream>>>(f2bf, w3p, det_b3, d3out, 256);
    pool_kernel<<<64, blk, 0, stream>>>(d3out, pooled);
    fc_argmax_kernel<<<1, 256, 0, stream>>>(pooled, fc_w, fc_b, pred);

    // ---- gated color-space branch (fp32 exact; zero cost if pred==0) ----
    conv3x3_kernel<<<dim3(144, 8, BB), blk, 0, stream>>>(x, 32, hvi_w1, hvi_b1, ycc_w1, ycc_b1, pred, t1, 64);
    conv3x3_kernel<<<dim3(144, 4, BB), blk, 0, stream>>>(t1, 64, hvi_w2, hvi_b2, ycc_w2, ycc_b2, pred, xb, 32);

    // ---- fused LN + pw(1x1) -> qkvp ----
    lnpw_kernel<<<2304, blk, 0, stream>>>(x, xb, pred, ln_w, ln_b, pw_w, qkvp);

    // ---- q/k dw-on-the-fly + stats; v dw into q-channel slots ----
    qkdwstats_kernel<<<dim3(9, 32), blk, 0, stream>>>(qkvp, dw_w, stats);
    vdw_kernel<<<73728, blk, 0, stream>>>(qkvp, dw_w);
    attnmb_kernel<<<1, 256, 0, stream>>>(stats, temp, proj_w, Mb);

    // ---- epilogue ----
    e1_kernel<<<2304, blk, 0, stream>>>(qkvp, x, xb, pred, Mb, ff1_w);
    fdw_kernel<<<73728, blk, 0, stream>>>(qkvp, ffdw_w, out);
}

// Round 4
// 2516.545 us; speedup vs baseline: 2.1389x; 1.2346x over previous
//
#include <hip/hip_runtime.h>
#include <hip/hip_bf16.h>
#include <math.h>

#define HH 384
#define WW 384
#define HWSZ (HH*WW)   // 147456
#define BB 4

typedef __attribute__((ext_vector_type(8))) short short8;
typedef __attribute__((ext_vector_type(4))) float f32x4;

// ---- workspace layout (float offsets). TOTAL: 16384 + 56,623,104 fl = 226.6 MB
static const size_t OFF_MISC = 0;        // 16384 floats
static const size_t OFF_A    = 16384;    // big region, 56,623,104 floats
// region-A sequenced reuse (float offsets within A):
//   det phase:  x0 bf16   @0          (2,359,296 fl)
//               f1 bf16   @2,359,296  (4,718,592 fl)
//               f2 bf16   @7,077,888  (9,437,184 fl)
//               d3out bf16@16,515,072 (18,874,368 fl)  ends 35,389,440
//               W' bf16   @56,423,104 (193,536 fl)     ends 56,616,640
//   branch:     t1 fp32   @0          (37,748,736 fl)  (xb lives in d_out)
//   qkv:        qkvp fp32 @0          (56,623,104 fl)
// misc (float offsets):
static const size_t MISC_POOLED = 0;     // 256 floats
static const size_t MISC_PRED   = 1024;  // 1 int
static const size_t MISC_STATS  = 1056;  // 768 floats
static const size_t MISC_MB     = 2048;  // 4096 floats

__device__ __forceinline__ float waveSum(float v) {
#pragma unroll
    for (int off = 32; off > 0; off >>= 1) v += __shfl_down(v, off);
    return v;
}

__device__ __forceinline__ float gelu_exact(float v) {
    return 0.5f * v * (1.0f + erff(v * 0.70710678118654752f));
}

__device__ __forceinline__ unsigned short f2bf(float f) {
    __hip_bfloat16 h = __float2bfloat16(f);
    return *(unsigned short*)&h;
}
__device__ __forceinline__ float bf2f(unsigned short u) {
    unsigned int b = ((unsigned int)u) << 16;
    return __uint_as_float(b);
}

// ===========================================================================
// DETECTOR PATH (bf16 MFMA) — only argmax(logits[0]) is consumed.
// ===========================================================================

// x batch0: NCHW fp32 -> NHWC bf16
__global__ __launch_bounds__(256) void xcvt_kernel(
    const float* __restrict__ x, unsigned short* __restrict__ x0)
{
    int px = blockIdx.x * 256 + threadIdx.x;
    if (px >= HWSZ) return;
    unsigned short u[32];
#pragma unroll
    for (int c = 0; c < 32; ++c) u[c] = f2bf(x[(size_t)c * HWSZ + px]);
    uint4* dst = (uint4*)(x0 + (size_t)px * 32);
#pragma unroll
    for (int g = 0; g < 4; ++g) {
        uint4 v;
        v.x = (unsigned)u[g*8+0] | ((unsigned)u[g*8+1] << 16);
        v.y = (unsigned)u[g*8+2] | ((unsigned)u[g*8+3] << 16);
        v.z = (unsigned)u[g*8+4] | ((unsigned)u[g*8+5] << 16);
        v.w = (unsigned)u[g*8+6] | ((unsigned)u[g*8+7] << 16);
        dst[g] = v;
    }
}

// weights OIHW fp32 -> [co][e=dy*3+dx][ci] bf16
__global__ __launch_bounds__(256) void wcvt_kernel(
    const float* __restrict__ w, unsigned short* __restrict__ wp,
    int Cin, int total)
{
    int t = blockIdx.x * 256 + threadIdx.x;
    if (t >= total) return;
    int nine_cin = 9 * Cin;
    int co = t / nine_cin;
    int r = t - co * nine_cin;
    int e = r / Cin;
    int ci = r - e * Cin;
    wp[t] = f2bf(w[(size_t)co * nine_cin + ci * 9 + e]);
}

// implicit-GEMM 3x3 conv, pad=1, bias+ReLU, NHWC bf16.
// Block = 4 waves, row-aligned 64-px tile, ALL Cout in one block (waves split
// Cout -> input staged once, no co duplication). K-loop: 32-ch chunks staged
// to LDS (12.7 KB), B-frags ds_read_b128 (2-way bank alias = free), A-frags
// (weights) from L2. Per (e,chunk): NT*4 MFMA : 4 ds_read : NT global.
template<int CIN, int COUT>
__global__ __launch_bounds__(256) void mfma_conv2_kernel(
    const unsigned short* __restrict__ in,
    const unsigned short* __restrict__ wp,
    const float* __restrict__ bias,
    unsigned short* __restrict__ out)
{
    constexpr int NT = COUT / 64;            // co-subtiles (of 16) per wave
    __shared__ unsigned short s_in[3 * 66 * 32];   // 12672 B

    const int tid  = threadIdx.x;
    const int lane = tid & 63;
    const int wave = tid >> 6;
    const int nl   = lane & 15;              // px within subtile / co within subtile
    const int quad = lane >> 4;              // k-group
    const int row  = blockIdx.x / 6;
    const int x0   = (blockIdx.x % 6) * 64;
    const int co_w0 = wave * (COUT / 4);

    f32x4 acc[4][NT];
#pragma unroll
    for (int pg = 0; pg < 4; ++pg)
#pragma unroll
        for (int ct = 0; ct < NT; ++ct) acc[pg][ct] = (f32x4){0.f,0.f,0.f,0.f};

#pragma unroll
    for (int ci0 = 0; ci0 < CIN; ci0 += 32) {
        __syncthreads();   // protect LDS from previous chunk's readers
        // ---- stage 3 rows x 66 px x 32 ch (16B per task, 792 tasks) ----
        for (int idx = tid; idx < 792; idx += 256) {
            int qs   = idx & 3;
            int cell = idx >> 2;           // r*66 + px
            int px   = cell % 66;
            int r    = cell / 66;
            int gy   = row + r - 1;
            int gx   = x0 + px - 1;
            uint4 v = {0u,0u,0u,0u};
            if ((unsigned)gy < (unsigned)HH && (unsigned)gx < (unsigned)WW)
                v = *(const uint4*)(in + (size_t)(gy * WW + gx) * CIN + ci0 + qs * 8);
            *(uint4*)(s_in + cell * 32 + qs * 8) = v;
        }
        __syncthreads();
        // ---- compute: 9 taps ----
#pragma unroll
        for (int e = 0; e < 9; ++e) {
            const int er = e / 3, ec = e % 3;
            short8 bfrag[4];
#pragma unroll
            for (int pg = 0; pg < 4; ++pg)
                bfrag[pg] = *(const short8*)(s_in + ((er * 66 + pg * 16 + nl + ec) * 32 + quad * 8));
#pragma unroll
            for (int ct = 0; ct < NT; ++ct) {
                short8 afrag = *(const short8*)(wp
                    + (size_t)(co_w0 + ct * 16 + nl) * (9 * CIN) + e * CIN + ci0 + quad * 8);
#pragma unroll
                for (int pg = 0; pg < 4; ++pg)
                    acc[pg][ct] = __builtin_amdgcn_mfma_f32_16x16x32_bf16(afrag, bfrag[pg], acc[pg][ct], 0, 0, 0);
            }
        }
    }

    // ---- epilogue: D layout col(px)=lane&15, row(co)=quad*4+reg ----
#pragma unroll
    for (int pg = 0; pg < 4; ++pg) {
        int px = x0 + pg * 16 + nl;
        unsigned short* op = out + ((size_t)row * WW + px) * COUT;
#pragma unroll
        for (int ct = 0; ct < NT; ++ct) {
            int cb = co_w0 + ct * 16 + quad * 4;
            ushort4 v;
            v.x = f2bf(fmaxf(acc[pg][ct][0] + bias[cb + 0], 0.f));
            v.y = f2bf(fmaxf(acc[pg][ct][1] + bias[cb + 1], 0.f));
            v.z = f2bf(fmaxf(acc[pg][ct][2] + bias[cb + 2], 0.f));
            v.w = f2bf(fmaxf(acc[pg][ct][3] + bias[cb + 3], 0.f));
            *(ushort4*)(op + cb) = v;
        }
    }
}

// global-average-pool sums over det3 output [HW][256] bf16 -> pooled[256]
__global__ __launch_bounds__(256) void pool_kernel(
    const unsigned short* __restrict__ d3, float* __restrict__ pooled)
{
    __shared__ float s_pool[256];
    int t = threadIdx.x;
    s_pool[t] = 0.f;
    __syncthreads();
    int co8 = (t & 31) * 8;
    int pxg = t >> 5;
    float sums[8];
#pragma unroll
    for (int j = 0; j < 8; ++j) sums[j] = 0.f;
    int base = blockIdx.x * 2304 + pxg;
    for (int i = 0; i < 288; ++i) {
        int px = base + i * 8;
        const uint4* p = (const uint4*)(d3 + (size_t)px * 256 + co8);
        uint4 v = *p;
        unsigned int w[4] = {v.x, v.y, v.z, v.w};
#pragma unroll
        for (int g = 0; g < 4; ++g) {
            sums[g*2+0] += bf2f((unsigned short)(w[g] & 0xFFFF));
            sums[g*2+1] += bf2f((unsigned short)(w[g] >> 16));
        }
    }
#pragma unroll
    for (int j = 0; j < 8; ++j) atomicAdd(&s_pool[co8 + j], sums[j]);
    __syncthreads();
    atomicAdd(&pooled[t], s_pool[t]);
}

// ---------------------------------------------------------------------------
__global__ void fc_argmax_kernel(const float* __restrict__ pooled,
                                 const float* __restrict__ fcw,
                                 const float* __restrict__ fcb,
                                 int* __restrict__ pred)
{
    int t = threadIdx.x;
    float m = pooled[t] * (1.0f / (float)HWSZ);
    float p0 = m * fcw[t];
    float p1 = m * fcw[256 + t];
    float p2 = m * fcw[512 + t];
    p0 = waveSum(p0); p1 = waveSum(p1); p2 = waveSum(p2);
    __shared__ float rr[3][4];
    int wid = t >> 6, lane = t & 63;
    if (lane == 0) { rr[0][wid] = p0; rr[1][wid] = p1; rr[2][wid] = p2; }
    __syncthreads();
    if (t == 0) {
        float l0 = rr[0][0] + rr[0][1] + rr[0][2] + rr[0][3] + fcb[0];
        float l1 = rr[1][0] + rr[1][1] + rr[1][2] + rr[1][3] + fcb[1];
        float l2 = rr[2][0] + rr[2][1] + rr[2][2] + rr[2][3] + fcb[2];
        int best = 0; float bv = l0;
        if (l1 > bv) { best = 1; bv = l1; }
        if (l2 > bv) { best = 2; bv = l2; }
        *pred = best;
    }
}

// ===========================================================================
// BRANCH convs — exact fp32 path (gated: zero cost when pred==0).
// ===========================================================================
__global__ __launch_bounds__(256, 2) void conv3x3_kernel(
    const float* __restrict__ in, int Cin,
    const float* __restrict__ wA, const float* __restrict__ bA,
    const float* __restrict__ wB, const float* __restrict__ bB,
    const int* __restrict__ predp,
    float* __restrict__ out, int Cout)
{
    const float* wsel = wA;
    const float* bsel = bA;
    {
        int p = __builtin_amdgcn_readfirstlane(*predp);
        if (p == 0) return;
        if (p == 2) { wsel = wB; bsel = bB; }
    }

    __shared__ float s_in[8][10][132];

    const int tid = threadIdx.x;
    const int tx = tid & 31;
    const int ty = tid >> 5;
    const int tilesX = WW / 128;
    const int tX = blockIdx.x % tilesX;
    const int tY = blockIdx.x / tilesX;
    const int x0 = tX * 128;
    const int y0 = tY * 8;
    const int co0 = blockIdx.y * 8;
    const int b = blockIdx.z;

    float acc[4][8];
#pragma unroll
    for (int p4 = 0; p4 < 4; ++p4)
#pragma unroll
        for (int co = 0; co < 8; ++co) acc[p4][co] = 0.f;

    const float* inb = in + (size_t)b * Cin * HWSZ;

    for (int ci0 = 0; ci0 < Cin; ci0 += 8) {
        for (int idx = tid; idx < 8 * 10 * 130; idx += 256) {
            int ci = idx / 1300;
            int r = idx % 1300;
            int iy = r / 130;
            int ix = r % 130;
            int gy = y0 + iy - 1;
            int gx = x0 + ix - 1;
            float v = 0.f;
            if ((unsigned)gy < (unsigned)HH && (unsigned)gx < (unsigned)WW)
                v = inb[(size_t)(ci0 + ci) * HWSZ + gy * WW + gx];
            s_in[ci][iy][ix] = v;
        }
        __syncthreads();

#pragma unroll
        for (int ci = 0; ci < 8; ++ci) {
#pragma unroll
            for (int dy = 0; dy < 3; ++dy) {
                const float* row = &s_in[ci][ty + dy][tx * 4];
                float iv0 = row[0], iv1 = row[1], iv2 = row[2];
                float iv3 = row[3], iv4 = row[4], iv5 = row[5];
                const float* wrow = wsel + ((size_t)co0 * Cin + (ci0 + ci)) * 9 + dy * 3;
                const int wstride = Cin * 9;
#pragma unroll
                for (int dx = 0; dx < 3; ++dx) {
                    float a0 = (dx == 0) ? iv0 : (dx == 1) ? iv1 : iv2;
                    float a1 = (dx == 0) ? iv1 : (dx == 1) ? iv2 : iv3;
                    float a2 = (dx == 0) ? iv2 : (dx == 1) ? iv3 : iv4;
                    float a3 = (dx == 0) ? iv3 : (dx == 1) ? iv4 : iv5;
#pragma unroll
                    for (int co = 0; co < 8; ++co) {
                        float wv = wrow[co * wstride + dx];
                        acc[0][co] = fmaf(a0, wv, acc[0][co]);
                        acc[1][co] = fmaf(a1, wv, acc[1][co]);
                        acc[2][co] = fmaf(a2, wv, acc[2][co]);
                        acc[3][co] = fmaf(a3, wv, acc[3][co]);
                    }
                }
            }
        }
        __syncthreads();
    }

    const int ox = x0 + tx * 4;
    const int oy = y0 + ty;
#pragma unroll
    for (int co = 0; co < 8; ++co) {
        float bv = bsel[co0 + co];
        float4 v;
        v.x = fmaxf(acc[0][co] + bv, 0.f);
        v.y = fmaxf(acc[1][co] + bv, 0.f);
        v.z = fmaxf(acc[2][co] + bv, 0.f);
        v.w = fmaxf(acc[3][co] + bv, 0.f);
        *(float4*)&out[(size_t)(b * Cout + co0 + co) * HWSZ + oy * WW + ox] = v;
    }
}

// ===========================================================================
// NUMERIC CHAIN — fp32
// ===========================================================================
__global__ __launch_bounds__(256) void lnpw_kernel(
    const float* __restrict__ x, const float* __restrict__ xb,
    const int* __restrict__ predp,
    const float* __restrict__ lnw, const float* __restrict__ lnb,
    const float* __restrict__ pww,
    float* __restrict__ qkvp)
{
    int p = blockIdx.x * 256 + threadIdx.x;
    if (p >= BB * HWSZ) return;
    int pr = __builtin_amdgcn_readfirstlane(*predp);
    const float* src = (pr == 0) ? x : xb;
    int b = p / HWSZ, n = p % HWSZ;
    const float* sp = src + (size_t)b * 32 * HWSZ + n;
    float v[32];
    float mean = 0.f;
#pragma unroll
    for (int c = 0; c < 32; ++c) { v[c] = sp[(size_t)c * HWSZ]; mean += v[c]; }
    mean *= (1.f / 32.f);
    float var = 0.f;
#pragma unroll
    for (int c = 0; c < 32; ++c) { float d = v[c] - mean; var += d * d; }
    var *= (1.f / 32.f);
    float rstd = rsqrtf(var + 1e-6f);
#pragma unroll
    for (int c = 0; c < 32; ++c)
        v[c] = (v[c] - mean) * rstd * lnw[c] + lnb[c];

    float acc[96];
#pragma unroll
    for (int co = 0; co < 96; ++co) acc[co] = 0.f;
    for (int ci = 0; ci < 32; ++ci) {
        float va = v[ci];
#pragma unroll
        for (int co = 0; co < 96; ++co)
            acc[co] = fmaf(pww[co * 32 + ci], va, acc[co]);
    }
    float* op = qkvp + (size_t)b * 96 * HWSZ + n;
#pragma unroll
    for (int co = 0; co < 96; ++co) op[(size_t)co * HWSZ] = acc[co];
}

// q/k depthwise-3x3 on the fly + stats per (b,h). grid (72, 32).
__global__ __launch_bounds__(256) void qkdwstats_kernel(
    const float* __restrict__ qkvp, const float* __restrict__ dww,
    float* __restrict__ stats)
{
    int bh = blockIdx.y;
    int b = bh >> 3, h = bh & 7;
    const float* qbase = qkvp + ((size_t)b * 96 + h * 4) * HWSZ;
    const float* kbase = qkvp + ((size_t)b * 96 + 32 + h * 4) * HWSZ;
    const float* wq = dww + (h * 4) * 9;
    const float* wk = dww + (32 + h * 4) * 9;
    float s[16], qn[4], kn[4];
#pragma unroll
    for (int i = 0; i < 16; ++i) s[i] = 0.f;
#pragma unroll
    for (int i = 0; i < 4; ++i) { qn[i] = 0.f; kn[i] = 0.f; }
    int base = blockIdx.x * 2048 + threadIdx.x;   // 72 chunks * 2048 = 147456
    for (int i = 0; i < 8; ++i) {
        int n = base + i * 256;
        int y = n / WW, x = n % WW;
        float q[4], k[4];
#pragma unroll
        for (int l = 0; l < 4; ++l) { q[l] = 0.f; k[l] = 0.f; }
#pragma unroll
        for (int dy = 0; dy < 3; ++dy) {
            int gy = y + dy - 1;
            if ((unsigned)gy >= (unsigned)HH) continue;
#pragma unroll
            for (int dx = 0; dx < 3; ++dx) {
                int gx = x + dx - 1;
                if ((unsigned)gx >= (unsigned)WW) continue;
                int off = gy * WW + gx;
                int wi = dy * 3 + dx;
#pragma unroll
                for (int l = 0; l < 4; ++l) {
                    q[l] = fmaf(qbase[(size_t)l * HWSZ + off], wq[l * 9 + wi], q[l]);
                    k[l] = fmaf(kbase[(size_t)l * HWSZ + off], wk[l * 9 + wi], k[l]);
                }
            }
        }
#pragma unroll
        for (int c = 0; c < 4; ++c) {
            qn[c] = fmaf(q[c], q[c], qn[c]);
            kn[c] = fmaf(k[c], k[c], kn[c]);
#pragma unroll
            for (int d = 0; d < 4; ++d)
                s[c * 4 + d] = fmaf(q[c], k[d], s[c * 4 + d]);
        }
    }
    float* st = stats + bh * 24;
    int lane = threadIdx.x & 63;
#pragma unroll
    for (int i = 0; i < 16; ++i) {
        float v = waveSum(s[i]);
        if (lane == 0) atomicAdd(&st[i], v);
    }
#pragma unroll
    for (int i = 0; i < 4; ++i) {
        float v = waveSum(qn[i]);
        if (lane == 0) atomicAdd(&st[16 + i], v);
        float u = waveSum(kn[i]);
        if (lane == 0) atomicAdd(&st[20 + i], u);
    }
}

__global__ __launch_bounds__(256) void vdw_kernel(
    float* __restrict__ qkvp, const float* __restrict__ dww)
{
    size_t idx = (size_t)blockIdx.x * 256 + threadIdx.x;
    int n = (int)(idx % HWSZ);
    int bc = (int)(idx / HWSZ);
    int b = bc >> 5, c = bc & 31;
    const float* ip = qkvp + ((size_t)b * 96 + 64 + c) * HWSZ;
    const float* wc = dww + (64 + c) * 9;
    int y = n / WW, x = n % WW;
    float s = 0.f;
#pragma unroll
    for (int dy = 0; dy < 3; ++dy) {
        int gy = y + dy - 1;
        if ((unsigned)gy >= (unsigned)HH) continue;
#pragma unroll
        for (int dx = 0; dx < 3; ++dx) {
            int gx = x + dx - 1;
            if ((unsigned)gx >= (unsigned)WW) continue;
            s = fmaf(ip[gy * WW + gx], wc[dy * 3 + dx], s);
        }
    }
    qkvp[((size_t)b * 96 + c) * HWSZ + n] = s;
}

__global__ void attnmb_kernel(const float* __restrict__ stats,
                              const float* __restrict__ temp,
                              const float* __restrict__ projw,
                              float* __restrict__ Mb)
{
    __shared__ float attn_s[4][8][4][4];
    int t = threadIdx.x;
    if (t < 128) {
        int b = t >> 5;
        int h = (t >> 2) & 7;
        int c = t & 3;
        const float* st = stats + (b * 8 + h) * 24;
        float qn = fmaxf(sqrtf(st[16 + c]), 1e-12f);
        float tp = temp[h];
        float raw[4];
#pragma unroll
        for (int d = 0; d < 4; ++d) {
            float kn = fmaxf(sqrtf(st[20 + d]), 1e-12f);
            raw[d] = st[c * 4 + d] / (qn * kn) * tp;
        }
        float m = fmaxf(fmaxf(raw[0], raw[1]), fmaxf(raw[2], raw[3]));
        float e0 = expf(raw[0] - m), e1 = expf(raw[1] - m);
        float e2 = expf(raw[2] - m), e3 = expf(raw[3] - m);
        float inv = 1.f / (e0 + e1 + e2 + e3);
        attn_s[b][h][c][0] = e0 * inv;
        attn_s[b][h][c][1] = e1 * inv;
        attn_s[b][h][c][2] = e2 * inv;
        attn_s[b][h][c][3] = e3 * inv;
    }
    __syncthreads();
    for (int idx = t; idx < 4096; idx += 256) {
        int b = idx >> 10;
        int r = idx & 1023;
        int co = r >> 5;
        int j = r & 31;
        int h = j >> 2;
        int d = j & 3;
        float m = 0.f;
#pragma unroll
        for (int l = 0; l < 4; ++l)
            m = fmaf(projw[co * 32 + h * 4 + l], attn_s[b][h][l][d], m);
        Mb[idx] = m;
    }
}

__global__ __launch_bounds__(256) void e1_kernel(
    float* __restrict__ qkvp, const float* __restrict__ x,
    const float* __restrict__ xb, const int* __restrict__ predp,
    const float* __restrict__ Mb, const float* __restrict__ ff1w)
{
    int p = blockIdx.x * 256 + threadIdx.x;
    if (p >= BB * HWSZ) return;
    int pr = __builtin_amdgcn_readfirstlane(*predp);
    const float* src = (pr == 0) ? x : xb;
    int b = p / HWSZ, n = p % HWSZ;
    float* vp = qkvp + (size_t)b * 96 * HWSZ + n;
    const float* Mbb = Mb + b * 1024;
    float y[32];
#pragma unroll
    for (int c = 0; c < 32; ++c) y[c] = 0.f;
    for (int j = 0; j < 32; ++j) {
        float vj = vp[(size_t)j * HWSZ];
#pragma unroll
        for (int co = 0; co < 32; ++co)
            y[co] = fmaf(Mbb[co * 32 + j], vj, y[co]);
    }
    const float* xp = src + (size_t)b * 32 * HWSZ + n;
#pragma unroll
    for (int c = 0; c < 32; ++c) y[c] += xp[(size_t)c * HWSZ];
    for (int co = 0; co < 32; ++co) {
        float s = 0.f;
#pragma unroll
        for (int ci = 0; ci < 32; ++ci)
            s = fmaf(ff1w[co * 32 + ci], y[ci], s);
        vp[(size_t)co * HWSZ] = gelu_exact(s);
    }
}

__global__ __launch_bounds__(256) void fdw_kernel(
    const float* __restrict__ z1, const float* __restrict__ w,
    float* __restrict__ out)
{
    size_t idx = (size_t)blockIdx.x * 256 + threadIdx.x;
    int n = (int)(idx % HWSZ);
    int bc = (int)(idx / HWSZ);
    int b = bc >> 5, c = bc & 31;
    const float* ip = z1 + ((size_t)b * 96 + c) * HWSZ;
    const float* wc = w + c * 9;
    int y = n / WW, x = n % WW;
    float s = 0.f;
#pragma unroll
    for (int dy = 0; dy < 3; ++dy) {
        int gy = y + dy - 1;
        if ((unsigned)gy >= (unsigned)HH) continue;
#pragma unroll
        for (int dx = 0; dx < 3; ++dx) {
            int gx = x + dx - 1;
            if ((unsigned)gx >= (unsigned)WW) continue;
            s = fmaf(ip[gy * WW + gx], wc[dy * 3 + dx], s);
        }
    }
    out[((size_t)b * 32 + c) * HWSZ + n] = gelu_exact(s);
}

// ---------------------------------------------------------------------------
extern "C" void kernel_launch(void* const* d_in, const int* in_sizes, int n_in,
                              void* d_out, int out_size, void* d_ws, size_t ws_size,
                              hipStream_t stream)
{
    (void)in_sizes; (void)n_in; (void)out_size; (void)ws_size;
    const float* x      = (const float*)d_in[0];
    const float* ln_w   = (const float*)d_in[1];
    const float* ln_b   = (const float*)d_in[2];
    const float* temp   = (const float*)d_in[3];
    const float* pw_w   = (const float*)d_in[4];
    const float* dw_w   = (const float*)d_in[5];
    const float* proj_w = (const float*)d_in[6];
    const float* ff1_w  = (const float*)d_in[7];
    const float* ffdw_w = (const float*)d_in[8];
    const float* det_w1 = (const float*)d_in[9];
    const float* det_b1 = (const float*)d_in[10];
    const float* det_w2 = (const float*)d_in[11];
    const float* det_b2 = (const float*)d_in[12];
    const float* det_w3 = (const float*)d_in[13];
    const float* det_b3 = (const float*)d_in[14];
    const float* fc_w   = (const float*)d_in[15];
    const float* fc_b   = (const float*)d_in[16];
    const float* hvi_w1 = (const float*)d_in[17];
    const float* hvi_b1 = (const float*)d_in[18];
    const float* hvi_w2 = (const float*)d_in[19];
    const float* hvi_b2 = (const float*)d_in[20];
    const float* ycc_w1 = (const float*)d_in[21];
    const float* ycc_b1 = (const float*)d_in[22];
    const float* ycc_w2 = (const float*)d_in[23];
    const float* ycc_b2 = (const float*)d_in[24];

    float* ws     = (float*)d_ws;
    float* misc   = ws + OFF_MISC;
    float* A      = ws + OFF_A;
    unsigned short* x0bf  = (unsigned short*)A;
    unsigned short* f1bf  = (unsigned short*)(A + 2359296);
    unsigned short* f2bf  = (unsigned short*)(A + 7077888);
    unsigned short* d3out = (unsigned short*)(A + 16515072);
    unsigned short* w1p   = (unsigned short*)(A + 56423104);
    unsigned short* w2p   = (unsigned short*)(A + 56432320);
    unsigned short* w3p   = (unsigned short*)(A + 56469184);
    float* t1     = A;
    float* qkvp   = A;
    float* xb     = (float*)d_out;
    float* pooled = misc + MISC_POOLED;
    int*   pred   = (int*)(misc + MISC_PRED);
    float* stats  = misc + MISC_STATS;
    float* Mb     = misc + MISC_MB;
    float* out    = (float*)d_out;

    hipMemsetAsync(misc, 0, 2048 * sizeof(float), stream);

    dim3 blk(256);
    // ---- weight + input conversion for MFMA detector ----
    wcvt_kernel<<<(18432 + 255) / 256, blk, 0, stream>>>(det_w1, w1p, 32, 18432);
    wcvt_kernel<<<(73728 + 255) / 256, blk, 0, stream>>>(det_w2, w2p, 64, 73728);
    wcvt_kernel<<<(294912 + 255) / 256, blk, 0, stream>>>(det_w3, w3p, 128, 294912);
    xcvt_kernel<<<576, blk, 0, stream>>>(x, x0bf);

    // ---- detector (batch 0 only; feeds argmax) ----
    mfma_conv2_kernel<32, 64>  <<<2304, blk, 0, stream>>>(x0bf, w1p, det_b1, f1bf);
    mfma_conv2_kernel<64, 128> <<<2304, blk, 0, stream>>>(f1bf, w2p, det_b2, f2bf);
    mfma_conv2_kernel<128, 256><<<2304, blk, 0, stream>>>(f2bf, w3p, det_b3, d3out);
    pool_kernel<<<64, blk, 0, stream>>>(d3out, pooled);
    fc_argmax_kernel<<<1, 256, 0, stream>>>(pooled, fc_w, fc_b, pred);

    // ---- gated color-space branch (fp32 exact; zero cost if pred==0) ----
    conv3x3_kernel<<<dim3(144, 8, BB), blk, 0, stream>>>(x, 32, hvi_w1, hvi_b1, ycc_w1, ycc_b1, pred, t1, 64);
    conv3x3_kernel<<<dim3(144, 4, BB), blk, 0, stream>>>(t1, 64, hvi_w2, hvi_b2, ycc_w2, ycc_b2, pred, xb, 32);

    // ---- fused LN + pw(1x1) -> qkvp ----
    lnpw_kernel<<<2304, blk, 0, stream>>>(x, xb, pred, ln_w, ln_b, pw_w, qkvp);

    // ---- q/k dw-on-the-fly + stats; v dw into q-channel slots ----
    qkdwstats_kernel<<<dim3(72, 32), blk, 0, stream>>>(qkvp, dw_w, stats);
    vdw_kernel<<<73728, blk, 0, stream>>>(qkvp, dw_w);
    attnmb_kernel<<<1, 256, 0, stream>>>(stats, temp, proj_w, Mb);

    // ---- epilogue ----
    e1_kernel<<<2304, blk, 0, stream>>>(qkvp, x, xb, pred, Mb, ff1_w);
    fdw_kernel<<<73728, blk, 0, stream>>>(qkvp, ffdw_w, out);
}

// Round 5
// 1538.215 us; speedup vs baseline: 3.4994x; 1.6360x over previous
//
#include <hip/hip_runtime.h>
#include <hip/hip_bf16.h>
#include <math.h>

#define HH 384
#define WW 384
#define HWSZ (HH*WW)   // 147456
#define BB 4

typedef __attribute__((ext_vector_type(8))) short short8;
typedef __attribute__((ext_vector_type(4))) float f32x4;

// ---- workspace layout (float offsets). TOTAL: 16384 + 56,623,104 + 73,728
// = 56,713,216 fl = 226.9 MB (226.6 proved OK in r2-r4).
static const size_t OFF_MISC = 0;        // 16384 floats
static const size_t OFF_A    = 16384;    // big region, 56,623,104 floats
static const size_t OFF_BW   = OFF_A + 56623104;   // 73,728 fl branch weights
// region-A sequenced reuse (float offsets within A):
//   det phase:  x0 bf16   @0          ; f1 bf16 @2,359,296 ; f2 bf16 @7,077,888
//               d3out bf16@16,515,072 (ends 35,389,440)
//               det W' bf16 @56,423,104 (ends 56,616,640)
//   branch:     xs_hi @0 (9.44M fl) ; xs_lo @9.44M ; t1_hi @18.87M ; t1_lo @37.75M
//               (t1_lo overwrites det W' - dead by then; xb lives in d_out)
//   qkv:        qkvp fp32 @0 (56,623,104 fl)
// misc (float offsets):
static const size_t MISC_POOLED = 0;     // 256 floats
static const size_t MISC_PRED   = 1024;  // 1 int
static const size_t MISC_STATS  = 1056;  // 768 floats
static const size_t MISC_MB     = 2048;  // 4096 floats

#define LPAD 40   // LDS row stride in ushorts: (cell*80+quad*16)/4 %32 covers
                  // all 32 banks 2-way (free) vs stride 32's 8-way conflict.

__device__ __forceinline__ float waveSum(float v) {
#pragma unroll
    for (int off = 32; off > 0; off >>= 1) v += __shfl_down(v, off);
    return v;
}

__device__ __forceinline__ float gelu_exact(float v) {
    return 0.5f * v * (1.0f + erff(v * 0.70710678118654752f));
}

__device__ __forceinline__ unsigned short f2bf(float f) {
    __hip_bfloat16 h = __float2bfloat16(f);
    return *(unsigned short*)&h;
}
__device__ __forceinline__ float bf2f(unsigned short u) {
    unsigned int b = ((unsigned int)u) << 16;
    return __uint_as_float(b);
}

// ===========================================================================
// DETECTOR PATH (bf16 MFMA) — only argmax(logits[0]) is consumed.
// ===========================================================================

// x batch0: NCHW fp32 -> NHWC bf16
__global__ __launch_bounds__(256) void xcvt_kernel(
    const float* __restrict__ x, unsigned short* __restrict__ x0)
{
    int px = blockIdx.x * 256 + threadIdx.x;
    if (px >= HWSZ) return;
    unsigned short u[32];
#pragma unroll
    for (int c = 0; c < 32; ++c) u[c] = f2bf(x[(size_t)c * HWSZ + px]);
    uint4* dst = (uint4*)(x0 + (size_t)px * 32);
#pragma unroll
    for (int g = 0; g < 4; ++g) {
        uint4 v;
        v.x = (unsigned)u[g*8+0] | ((unsigned)u[g*8+1] << 16);
        v.y = (unsigned)u[g*8+2] | ((unsigned)u[g*8+3] << 16);
        v.z = (unsigned)u[g*8+4] | ((unsigned)u[g*8+5] << 16);
        v.w = (unsigned)u[g*8+6] | ((unsigned)u[g*8+7] << 16);
        dst[g] = v;
    }
}

// weights OIHW fp32 -> [co][e=dy*3+dx][ci] bf16
__global__ __launch_bounds__(256) void wcvt_kernel(
    const float* __restrict__ w, unsigned short* __restrict__ wp,
    int Cin, int total)
{
    int t = blockIdx.x * 256 + threadIdx.x;
    if (t >= total) return;
    int nine_cin = 9 * Cin;
    int co = t / nine_cin;
    int r = t - co * nine_cin;
    int e = r / Cin;
    int ci = r - e * Cin;
    wp[t] = f2bf(w[(size_t)co * nine_cin + ci * 9 + e]);
}

// implicit-GEMM 3x3 conv, pad=1, bias+ReLU, NHWC bf16 (detector).
template<int CIN, int COUT>
__global__ __launch_bounds__(256) void mfma_conv2_kernel(
    const unsigned short* __restrict__ in,
    const unsigned short* __restrict__ wp,
    const float* __restrict__ bias,
    unsigned short* __restrict__ out)
{
    constexpr int NT = COUT / 64;
    __shared__ unsigned short s_in[198 * LPAD];

    const int tid  = threadIdx.x;
    const int lane = tid & 63;
    const int wave = tid >> 6;
    const int nl   = lane & 15;
    const int quad = lane >> 4;
    const int row  = blockIdx.x / 6;
    const int x0   = (blockIdx.x % 6) * 64;
    const int co_w0 = wave * (COUT / 4);

    f32x4 acc[4][NT];
#pragma unroll
    for (int pg = 0; pg < 4; ++pg)
#pragma unroll
        for (int ct = 0; ct < NT; ++ct) acc[pg][ct] = (f32x4){0.f,0.f,0.f,0.f};

#pragma unroll
    for (int ci0 = 0; ci0 < CIN; ci0 += 32) {
        __syncthreads();
        for (int idx = tid; idx < 792; idx += 256) {
            int qs   = idx & 3;
            int cell = idx >> 2;
            int px   = cell % 66;
            int r    = cell / 66;
            int gy   = row + r - 1;
            int gx   = x0 + px - 1;
            uint4 v = {0u,0u,0u,0u};
            if ((unsigned)gy < (unsigned)HH && (unsigned)gx < (unsigned)WW)
                v = *(const uint4*)(in + (size_t)(gy * WW + gx) * CIN + ci0 + qs * 8);
            *(uint4*)(s_in + cell * LPAD + qs * 8) = v;
        }
        __syncthreads();
#pragma unroll
        for (int e = 0; e < 9; ++e) {
            const int er = e / 3, ec = e % 3;
            short8 bfrag[4];
#pragma unroll
            for (int pg = 0; pg < 4; ++pg)
                bfrag[pg] = *(const short8*)(s_in + ((er * 66 + pg * 16 + nl + ec) * LPAD + quad * 8));
#pragma unroll
            for (int ct = 0; ct < NT; ++ct) {
                short8 afrag = *(const short8*)(wp
                    + (size_t)(co_w0 + ct * 16 + nl) * (9 * CIN) + e * CIN + ci0 + quad * 8);
#pragma unroll
                for (int pg = 0; pg < 4; ++pg)
                    acc[pg][ct] = __builtin_amdgcn_mfma_f32_16x16x32_bf16(afrag, bfrag[pg], acc[pg][ct], 0, 0, 0);
            }
        }
    }

#pragma unroll
    for (int pg = 0; pg < 4; ++pg) {
        int px = x0 + pg * 16 + nl;
        unsigned short* op = out + ((size_t)row * WW + px) * COUT;
#pragma unroll
        for (int ct = 0; ct < NT; ++ct) {
            int cb = co_w0 + ct * 16 + quad * 4;
            ushort4 v;
            v.x = f2bf(fmaxf(acc[pg][ct][0] + bias[cb + 0], 0.f));
            v.y = f2bf(fmaxf(acc[pg][ct][1] + bias[cb + 1], 0.f));
            v.z = f2bf(fmaxf(acc[pg][ct][2] + bias[cb + 2], 0.f));
            v.w = f2bf(fmaxf(acc[pg][ct][3] + bias[cb + 3], 0.f));
            *(ushort4*)(op + cb) = v;
        }
    }
}

// global-average-pool sums over det3 output [HW][256] bf16 -> pooled[256]
__global__ __launch_bounds__(256) void pool_kernel(
    const unsigned short* __restrict__ d3, float* __restrict__ pooled)
{
    __shared__ float s_pool[256];
    int t = threadIdx.x;
    s_pool[t] = 0.f;
    __syncthreads();
    int co8 = (t & 31) * 8;
    int pxg = t >> 5;
    float sums[8];
#pragma unroll
    for (int j = 0; j < 8; ++j) sums[j] = 0.f;
    int base = blockIdx.x * 2304 + pxg;
    for (int i = 0; i < 288; ++i) {
        int px = base + i * 8;
        const uint4* p = (const uint4*)(d3 + (size_t)px * 256 + co8);
        uint4 v = *p;
        unsigned int w[4] = {v.x, v.y, v.z, v.w};
#pragma unroll
        for (int g = 0; g < 4; ++g) {
            sums[g*2+0] += bf2f((unsigned short)(w[g] & 0xFFFF));
            sums[g*2+1] += bf2f((unsigned short)(w[g] >> 16));
        }
    }
#pragma unroll
    for (int j = 0; j < 8; ++j) atomicAdd(&s_pool[co8 + j], sums[j]);
    __syncthreads();
    atomicAdd(&pooled[t], s_pool[t]);
}

__global__ void fc_argmax_kernel(const float* __restrict__ pooled,
                                 const float* __restrict__ fcw,
                                 const float* __restrict__ fcb,
                                 int* __restrict__ pred)
{
    int t = threadIdx.x;
    float m = pooled[t] * (1.0f / (float)HWSZ);
    float p0 = m * fcw[t];
    float p1 = m * fcw[256 + t];
    float p2 = m * fcw[512 + t];
    p0 = waveSum(p0); p1 = waveSum(p1); p2 = waveSum(p2);
    __shared__ float rr[3][4];
    int wid = t >> 6, lane = t & 63;
    if (lane == 0) { rr[0][wid] = p0; rr[1][wid] = p1; rr[2][wid] = p2; }
    __syncthreads();
    if (t == 0) {
        float l0 = rr[0][0] + rr[0][1] + rr[0][2] + rr[0][3] + fcb[0];
        float l1 = rr[1][0] + rr[1][1] + rr[1][2] + rr[1][3] + fcb[1];
        float l2 = rr[2][0] + rr[2][1] + rr[2][2] + rr[2][3] + fcb[2];
        int best = 0; float bv = l0;
        if (l1 > bv) { best = 1; bv = l1; }
        if (l2 > bv) { best = 2; bv = l2; }
        *pred = best;
    }
}

// ===========================================================================
// BRANCH convs — bf16 hi/lo 3-MFMA emulation (~fp19 per product; error ~1e-5).
// Gated: early-return when pred==0.
// ===========================================================================

// split weights OIHW fp32 -> [co][e][ci] bf16 hi + lo
__global__ __launch_bounds__(256) void wsplit_kernel(
    const float* __restrict__ w,
    unsigned short* __restrict__ hi, unsigned short* __restrict__ lo,
    int Cin, int total)
{
    int t = blockIdx.x * 256 + threadIdx.x;
    if (t >= total) return;
    int nine_cin = 9 * Cin;
    int co = t / nine_cin;
    int r = t - co * nine_cin;
    int e = r / Cin;
    int ci = r - e * Cin;
    float v = w[(size_t)co * nine_cin + ci * 9 + e];
    unsigned short h = f2bf(v);
    hi[t] = h;
    lo[t] = f2bf(v - bf2f(h));
}

// x all batches: NCHW fp32 -> NHWC bf16 hi + lo (gated)
__global__ __launch_bounds__(256) void xsplitb_kernel(
    const float* __restrict__ x, const int* __restrict__ predp,
    unsigned short* __restrict__ hi, unsigned short* __restrict__ lo)
{
    if (__builtin_amdgcn_readfirstlane(*predp) == 0) return;
    int p = blockIdx.x * 256 + threadIdx.x;
    if (p >= BB * HWSZ) return;
    int b = p / HWSZ, n = p % HWSZ;
    const float* sp = x + (size_t)b * 32 * HWSZ + n;
    unsigned short uh[32], ul[32];
#pragma unroll
    for (int c = 0; c < 32; ++c) {
        float v = sp[(size_t)c * HWSZ];
        unsigned short h = f2bf(v);
        uh[c] = h;
        ul[c] = f2bf(v - bf2f(h));
    }
    uint4* dh = (uint4*)(hi + (size_t)p * 32);
    uint4* dl = (uint4*)(lo + (size_t)p * 32);
#pragma unroll
    for (int g = 0; g < 4; ++g) {
        uint4 vh, vl;
        vh.x = (unsigned)uh[g*8+0] | ((unsigned)uh[g*8+1] << 16);
        vh.y = (unsigned)uh[g*8+2] | ((unsigned)uh[g*8+3] << 16);
        vh.z = (unsigned)uh[g*8+4] | ((unsigned)uh[g*8+5] << 16);
        vh.w = (unsigned)uh[g*8+6] | ((unsigned)uh[g*8+7] << 16);
        vl.x = (unsigned)ul[g*8+0] | ((unsigned)ul[g*8+1] << 16);
        vl.y = (unsigned)ul[g*8+2] | ((unsigned)ul[g*8+3] << 16);
        vl.z = (unsigned)ul[g*8+4] | ((unsigned)ul[g*8+5] << 16);
        vl.w = (unsigned)ul[g*8+6] | ((unsigned)ul[g*8+7] << 16);
        dh[g] = vh;
        dl[g] = vl;
    }
}

// branch 3x3 conv, pad=1, bias+ReLU, hi/lo bf16 in, 3-MFMA per tap-chunk.
// OUTMODE 0: write bf16 hi/lo NHWC (t1). OUTMODE 1: write fp32 NCHW (xb).
template<int CIN, int COUT, int OUTMODE>
__global__ __launch_bounds__(256) void bconv_kernel(
    const unsigned short* __restrict__ in_hi, const unsigned short* __restrict__ in_lo,
    const unsigned short* __restrict__ wAh, const unsigned short* __restrict__ wAl,
    const unsigned short* __restrict__ wBh, const unsigned short* __restrict__ wBl,
    const float* __restrict__ bA, const float* __restrict__ bB,
    const int* __restrict__ predp,
    unsigned short* __restrict__ out_hi, unsigned short* __restrict__ out_lo,
    float* __restrict__ out_f32)
{
    const int p = __builtin_amdgcn_readfirstlane(*predp);
    if (p == 0) return;
    const unsigned short* whi = (p == 1) ? wAh : wBh;
    const unsigned short* wlo = (p == 1) ? wAl : wBl;
    const float* bias = (p == 1) ? bA : bB;

    constexpr int NPG = (COUT == 64) ? 4 : 2;
    __shared__ unsigned short s_hi[198 * LPAD];
    __shared__ unsigned short s_lo[198 * LPAD];

    const int tid  = threadIdx.x;
    const int lane = tid & 63;
    const int wave = tid >> 6;
    const int nl   = lane & 15;
    const int quad = lane >> 4;
    const int row  = blockIdx.x / 6;
    const int x0   = (blockIdx.x % 6) * 64;
    const int b    = blockIdx.y;
    const int co_w0 = (COUT == 64) ? wave * 16 : (wave & 1) * 16;
    const int pg0   = (COUT == 64) ? 0 : (wave >> 1) * 2;

    f32x4 acc[NPG];
#pragma unroll
    for (int g = 0; g < NPG; ++g) acc[g] = (f32x4){0.f,0.f,0.f,0.f};

    const unsigned short* ibh = in_hi + (size_t)b * HWSZ * CIN;
    const unsigned short* ibl = in_lo + (size_t)b * HWSZ * CIN;

#pragma unroll
    for (int ci0 = 0; ci0 < CIN; ci0 += 32) {
        __syncthreads();
        for (int idx = tid; idx < 792; idx += 256) {
            int qs   = idx & 3;
            int cell = idx >> 2;
            int px   = cell % 66;
            int r    = cell / 66;
            int gy   = row + r - 1;
            int gx   = x0 + px - 1;
            uint4 vh = {0u,0u,0u,0u}, vl = {0u,0u,0u,0u};
            if ((unsigned)gy < (unsigned)HH && (unsigned)gx < (unsigned)WW) {
                size_t base = (size_t)(gy * WW + gx) * CIN + ci0 + qs * 8;
                vh = *(const uint4*)(ibh + base);
                vl = *(const uint4*)(ibl + base);
            }
            *(uint4*)(s_hi + cell * LPAD + qs * 8) = vh;
            *(uint4*)(s_lo + cell * LPAD + qs * 8) = vl;
        }
        __syncthreads();
#pragma unroll
        for (int e = 0; e < 9; ++e) {
            const int er = e / 3, ec = e % 3;
            size_t woff = (size_t)(co_w0 + nl) * (9 * CIN) + e * CIN + ci0 + quad * 8;
            short8 ah = *(const short8*)(whi + woff);
            short8 al = *(const short8*)(wlo + woff);
#pragma unroll
            for (int g = 0; g < NPG; ++g) {
                int cell = er * 66 + (pg0 + g) * 16 + nl + ec;
                short8 bh = *(const short8*)(s_hi + cell * LPAD + quad * 8);
                short8 bl = *(const short8*)(s_lo + cell * LPAD + quad * 8);
                acc[g] = __builtin_amdgcn_mfma_f32_16x16x32_bf16(ah, bh, acc[g], 0, 0, 0);
                acc[g] = __builtin_amdgcn_mfma_f32_16x16x32_bf16(ah, bl, acc[g], 0, 0, 0);
                acc[g] = __builtin_amdgcn_mfma_f32_16x16x32_bf16(al, bh, acc[g], 0, 0, 0);
            }
        }
    }

    const int cb = co_w0 + quad * 4;
#pragma unroll
    for (int g = 0; g < NPG; ++g) {
        int px = x0 + (pg0 + g) * 16 + nl;
        float r0 = fmaxf(acc[g][0] + bias[cb + 0], 0.f);
        float r1 = fmaxf(acc[g][1] + bias[cb + 1], 0.f);
        float r2 = fmaxf(acc[g][2] + bias[cb + 2], 0.f);
        float r3 = fmaxf(acc[g][3] + bias[cb + 3], 0.f);
        if (OUTMODE == 0) {
            size_t base = ((size_t)b * HWSZ + row * WW + px) * COUT + cb;
            ushort4 vh, vl;
            unsigned short h;
            h = f2bf(r0); vh.x = h; vl.x = f2bf(r0 - bf2f(h));
            h = f2bf(r1); vh.y = h; vl.y = f2bf(r1 - bf2f(h));
            h = f2bf(r2); vh.z = h; vl.z = f2bf(r2 - bf2f(h));
            h = f2bf(r3); vh.w = h; vl.w = f2bf(r3 - bf2f(h));
            *(ushort4*)(out_hi + base) = vh;
            *(ushort4*)(out_lo + base) = vl;
        } else {
            size_t sp = (size_t)row * WW + px;
            out_f32[((size_t)b * COUT + cb + 0) * HWSZ + sp] = r0;
            out_f32[((size_t)b * COUT + cb + 1) * HWSZ + sp] = r1;
            out_f32[((size_t)b * COUT + cb + 2) * HWSZ + sp] = r2;
            out_f32[((size_t)b * COUT + cb + 3) * HWSZ + sp] = r3;
        }
    }
}

// ===========================================================================
// NUMERIC CHAIN — fp32
// ===========================================================================
__global__ __launch_bounds__(256) void lnpw_kernel(
    const float* __restrict__ x, const float* __restrict__ xb,
    const int* __restrict__ predp,
    const float* __restrict__ lnw, const float* __restrict__ lnb,
    const float* __restrict__ pww,
    float* __restrict__ qkvp)
{
    int p = blockIdx.x * 256 + threadIdx.x;
    if (p >= BB * HWSZ) return;
    int pr = __builtin_amdgcn_readfirstlane(*predp);
    const float* src = (pr == 0) ? x : xb;
    int b = p / HWSZ, n = p % HWSZ;
    const float* sp = src + (size_t)b * 32 * HWSZ + n;
    float v[32];
    float mean = 0.f;
#pragma unroll
    for (int c = 0; c < 32; ++c) { v[c] = sp[(size_t)c * HWSZ]; mean += v[c]; }
    mean *= (1.f / 32.f);
    float var = 0.f;
#pragma unroll
    for (int c = 0; c < 32; ++c) { float d = v[c] - mean; var += d * d; }
    var *= (1.f / 32.f);
    float rstd = rsqrtf(var + 1e-6f);
#pragma unroll
    for (int c = 0; c < 32; ++c)
        v[c] = (v[c] - mean) * rstd * lnw[c] + lnb[c];

    float acc[96];
#pragma unroll
    for (int co = 0; co < 96; ++co) acc[co] = 0.f;
    for (int ci = 0; ci < 32; ++ci) {
        float va = v[ci];
#pragma unroll
        for (int co = 0; co < 96; ++co)
            acc[co] = fmaf(pww[co * 32 + ci], va, acc[co]);
    }
    float* op = qkvp + (size_t)b * 96 * HWSZ + n;
#pragma unroll
    for (int co = 0; co < 96; ++co) op[(size_t)co * HWSZ] = acc[co];
}

__global__ __launch_bounds__(256) void qkdwstats_kernel(
    const float* __restrict__ qkvp, const float* __restrict__ dww,
    float* __restrict__ stats)
{
    int bh = blockIdx.y;
    int b = bh >> 3, h = bh & 7;
    const float* qbase = qkvp + ((size_t)b * 96 + h * 4) * HWSZ;
    const float* kbase = qkvp + ((size_t)b * 96 + 32 + h * 4) * HWSZ;
    const float* wq = dww + (h * 4) * 9;
    const float* wk = dww + (32 + h * 4) * 9;
    float s[16], qn[4], kn[4];
#pragma unroll
    for (int i = 0; i < 16; ++i) s[i] = 0.f;
#pragma unroll
    for (int i = 0; i < 4; ++i) { qn[i] = 0.f; kn[i] = 0.f; }
    int base = blockIdx.x * 2048 + threadIdx.x;
    for (int i = 0; i < 8; ++i) {
        int n = base + i * 256;
        int y = n / WW, x = n % WW;
        float q[4], k[4];
#pragma unroll
        for (int l = 0; l < 4; ++l) { q[l] = 0.f; k[l] = 0.f; }
#pragma unroll
        for (int dy = 0; dy < 3; ++dy) {
            int gy = y + dy - 1;
            if ((unsigned)gy >= (unsigned)HH) continue;
#pragma unroll
            for (int dx = 0; dx < 3; ++dx) {
                int gx = x + dx - 1;
                if ((unsigned)gx >= (unsigned)WW) continue;
                int off = gy * WW + gx;
                int wi = dy * 3 + dx;
#pragma unroll
                for (int l = 0; l < 4; ++l) {
                    q[l] = fmaf(qbase[(size_t)l * HWSZ + off], wq[l * 9 + wi], q[l]);
                    k[l] = fmaf(kbase[(size_t)l * HWSZ + off], wk[l * 9 + wi], k[l]);
                }
            }
        }
#pragma unroll
        for (int c = 0; c < 4; ++c) {
            qn[c] = fmaf(q[c], q[c], qn[c]);
            kn[c] = fmaf(k[c], k[c], kn[c]);
#pragma unroll
            for (int d = 0; d < 4; ++d)
                s[c * 4 + d] = fmaf(q[c], k[d], s[c * 4 + d]);
        }
    }
    float* st = stats + bh * 24;
    int lane = threadIdx.x & 63;
#pragma unroll
    for (int i = 0; i < 16; ++i) {
        float v = waveSum(s[i]);
        if (lane == 0) atomicAdd(&st[i], v);
    }
#pragma unroll
    for (int i = 0; i < 4; ++i) {
        float v = waveSum(qn[i]);
        if (lane == 0) atomicAdd(&st[16 + i], v);
        float u = waveSum(kn[i]);
        if (lane == 0) atomicAdd(&st[20 + i], u);
    }
}

__global__ __launch_bounds__(256) void vdw_kernel(
    float* __restrict__ qkvp, const float* __restrict__ dww)
{
    size_t idx = (size_t)blockIdx.x * 256 + threadIdx.x;
    int n = (int)(idx % HWSZ);
    int bc = (int)(idx / HWSZ);
    int b = bc >> 5, c = bc & 31;
    const float* ip = qkvp + ((size_t)b * 96 + 64 + c) * HWSZ;
    const float* wc = dww + (64 + c) * 9;
    int y = n / WW, x = n % WW;
    float s = 0.f;
#pragma unroll
    for (int dy = 0; dy < 3; ++dy) {
        int gy = y + dy - 1;
        if ((unsigned)gy >= (unsigned)HH) continue;
#pragma unroll
        for (int dx = 0; dx < 3; ++dx) {
            int gx = x + dx - 1;
            if ((unsigned)gx >= (unsigned)WW) continue;
            s = fmaf(ip[gy * WW + gx], wc[dy * 3 + dx], s);
        }
    }
    qkvp[((size_t)b * 96 + c) * HWSZ + n] = s;
}

__global__ void attnmb_kernel(const float* __restrict__ stats,
                              const float* __restrict__ temp,
                              const float* __restrict__ projw,
                              float* __restrict__ Mb)
{
    __shared__ float attn_s[4][8][4][4];
    int t = threadIdx.x;
    if (t < 128) {
        int b = t >> 5;
        int h = (t >> 2) & 7;
        int c = t & 3;
        const float* st = stats + (b * 8 + h) * 24;
        float qn = fmaxf(sqrtf(st[16 + c]), 1e-12f);
        float tp = temp[h];
        float raw[4];
#pragma unroll
        for (int d = 0; d < 4; ++d) {
            float kn = fmaxf(sqrtf(st[20 + d]), 1e-12f);
            raw[d] = st[c * 4 + d] / (qn * kn) * tp;
        }
        float m = fmaxf(fmaxf(raw[0], raw[1]), fmaxf(raw[2], raw[3]));
        float e0 = expf(raw[0] - m), e1 = expf(raw[1] - m);
        float e2 = expf(raw[2] - m), e3 = expf(raw[3] - m);
        float inv = 1.f / (e0 + e1 + e2 + e3);
        attn_s[b][h][c][0] = e0 * inv;
        attn_s[b][h][c][1] = e1 * inv;
        attn_s[b][h][c][2] = e2 * inv;
        attn_s[b][h][c][3] = e3 * inv;
    }
    __syncthreads();
    for (int idx = t; idx < 4096; idx += 256) {
        int b = idx >> 10;
        int r = idx & 1023;
        int co = r >> 5;
        int j = r & 31;
        int h = j >> 2;
        int d = j & 3;
        float m = 0.f;
#pragma unroll
        for (int l = 0; l < 4; ++l)
            m = fmaf(projw[co * 32 + h * 4 + l], attn_s[b][h][l][d], m);
        Mb[idx] = m;
    }
}

__global__ __launch_bounds__(256) void e1_kernel(
    float* __restrict__ qkvp, const float* __restrict__ x,
    const float* __restrict__ xb, const int* __restrict__ predp,
    const float* __restrict__ Mb, const float* __restrict__ ff1w)
{
    int p = blockIdx.x * 256 + threadIdx.x;
    if (p >= BB * HWSZ) return;
    int pr = __builtin_amdgcn_readfirstlane(*predp);
    const float* src = (pr == 0) ? x : xb;
    int b = p / HWSZ, n = p % HWSZ;
    float* vp = qkvp + (size_t)b * 96 * HWSZ + n;
    const float* Mbb = Mb + b * 1024;
    float y[32];
#pragma unroll
    for (int c = 0; c < 32; ++c) y[c] = 0.f;
    for (int j = 0; j < 32; ++j) {
        float vj = vp[(size_t)j * HWSZ];
#pragma unroll
        for (int co = 0; co < 32; ++co)
            y[co] = fmaf(Mbb[co * 32 + j], vj, y[co]);
    }
    const float* xp = src + (size_t)b * 32 * HWSZ + n;
#pragma unroll
    for (int c = 0; c < 32; ++c) y[c] += xp[(size_t)c * HWSZ];
    for (int co = 0; co < 32; ++co) {
        float s = 0.f;
#pragma unroll
        for (int ci = 0; ci < 32; ++ci)
            s = fmaf(ff1w[co * 32 + ci], y[ci], s);
        vp[(size_t)co * HWSZ] = gelu_exact(s);
    }
}

__global__ __launch_bounds__(256) void fdw_kernel(
    const float* __restrict__ z1, const float* __restrict__ w,
    float* __restrict__ out)
{
    size_t idx = (size_t)blockIdx.x * 256 + threadIdx.x;
    int n = (int)(idx % HWSZ);
    int bc = (int)(idx / HWSZ);
    int b = bc >> 5, c = bc & 31;
    const float* ip = z1 + ((size_t)b * 96 + c) * HWSZ;
    const float* wc = w + c * 9;
    int y = n / WW, x = n % WW;
    float s = 0.f;
#pragma unroll
    for (int dy = 0; dy < 3; ++dy) {
        int gy = y + dy - 1;
        if ((unsigned)gy >= (unsigned)HH) continue;
#pragma unroll
        for (int dx = 0; dx < 3; ++dx) {
            int gx = x + dx - 1;
            if ((unsigned)gx >= (unsigned)WW) continue;
            s = fmaf(ip[gy * WW + gx], wc[dy * 3 + dx], s);
        }
    }
    out[((size_t)b * 32 + c) * HWSZ + n] = gelu_exact(s);
}

// ---------------------------------------------------------------------------
extern "C" void kernel_launch(void* const* d_in, const int* in_sizes, int n_in,
                              void* d_out, int out_size, void* d_ws, size_t ws_size,
                              hipStream_t stream)
{
    (void)in_sizes; (void)n_in; (void)out_size; (void)ws_size;
    const float* x      = (const float*)d_in[0];
    const float* ln_w   = (const float*)d_in[1];
    const float* ln_b   = (const float*)d_in[2];
    const float* temp   = (const float*)d_in[3];
    const float* pw_w   = (const float*)d_in[4];
    const float* dw_w   = (const float*)d_in[5];
    const float* proj_w = (const float*)d_in[6];
    const float* ff1_w  = (const float*)d_in[7];
    const float* ffdw_w = (const float*)d_in[8];
    const float* det_w1 = (const float*)d_in[9];
    const float* det_b1 = (const float*)d_in[10];
    const float* det_w2 = (const float*)d_in[11];
    const float* det_b2 = (const float*)d_in[12];
    const float* det_w3 = (const float*)d_in[13];
    const float* det_b3 = (const float*)d_in[14];
    const float* fc_w   = (const float*)d_in[15];
    const float* fc_b   = (const float*)d_in[16];
    const float* hvi_w1 = (const float*)d_in[17];
    const float* hvi_b1 = (const float*)d_in[18];
    const float* hvi_w2 = (const float*)d_in[19];
    const float* hvi_b2 = (const float*)d_in[20];
    const float* ycc_w1 = (const float*)d_in[21];
    const float* ycc_b1 = (const float*)d_in[22];
    const float* ycc_w2 = (const float*)d_in[23];
    const float* ycc_b2 = (const float*)d_in[24];

    float* ws     = (float*)d_ws;
    float* misc   = ws + OFF_MISC;
    float* A      = ws + OFF_A;
    // det phase
    unsigned short* x0bf  = (unsigned short*)A;
    unsigned short* f1bf  = (unsigned short*)(A + 2359296);
    unsigned short* f2bf  = (unsigned short*)(A + 7077888);
    unsigned short* d3out = (unsigned short*)(A + 16515072);
    unsigned short* w1p   = (unsigned short*)(A + 56423104);
    unsigned short* w2p   = (unsigned short*)(A + 56432320);
    unsigned short* w3p   = (unsigned short*)(A + 56469184);
    // branch phase
    unsigned short* xs_hi = (unsigned short*)A;
    unsigned short* xs_lo = (unsigned short*)(A + 9437184);
    unsigned short* t1_hi = (unsigned short*)(A + 18874368);
    unsigned short* t1_lo = (unsigned short*)(A + 37748736);
    unsigned short* bw    = (unsigned short*)(ws + OFF_BW);
    unsigned short* bw_h1h = bw;            unsigned short* bw_h1l = bw + 18432;
    unsigned short* bw_y1h = bw + 36864;    unsigned short* bw_y1l = bw + 55296;
    unsigned short* bw_h2h = bw + 73728;    unsigned short* bw_h2l = bw + 92160;
    unsigned short* bw_y2h = bw + 110592;   unsigned short* bw_y2l = bw + 129024;
    // qkv phase
    float* qkvp   = A;
    float* xb     = (float*)d_out;
    float* pooled = misc + MISC_POOLED;
    int*   pred   = (int*)(misc + MISC_PRED);
    float* stats  = misc + MISC_STATS;
    float* Mb     = misc + MISC_MB;
    float* out    = (float*)d_out;

    hipMemsetAsync(misc, 0, 2048 * sizeof(float), stream);

    dim3 blk(256);
    // ---- weight + input conversion ----
    wcvt_kernel<<<(18432 + 255) / 256, blk, 0, stream>>>(det_w1, w1p, 32, 18432);
    wcvt_kernel<<<(73728 + 255) / 256, blk, 0, stream>>>(det_w2, w2p, 64, 73728);
    wcvt_kernel<<<(294912 + 255) / 256, blk, 0, stream>>>(det_w3, w3p, 128, 294912);
    xcvt_kernel<<<576, blk, 0, stream>>>(x, x0bf);
    wsplit_kernel<<<72, blk, 0, stream>>>(hvi_w1, bw_h1h, bw_h1l, 32, 18432);
    wsplit_kernel<<<72, blk, 0, stream>>>(ycc_w1, bw_y1h, bw_y1l, 32, 18432);
    wsplit_kernel<<<72, blk, 0, stream>>>(hvi_w2, bw_h2h, bw_h2l, 64, 18432);
    wsplit_kernel<<<72, blk, 0, stream>>>(ycc_w2, bw_y2h, bw_y2l, 64, 18432);

    // ---- detector (batch 0 only; feeds argmax) ----
    mfma_conv2_kernel<32, 64>  <<<2304, blk, 0, stream>>>(x0bf, w1p, det_b1, f1bf);
    mfma_conv2_kernel<64, 128> <<<2304, blk, 0, stream>>>(f1bf, w2p, det_b2, f2bf);
    mfma_conv2_kernel<128, 256><<<2304, blk, 0, stream>>>(f2bf, w3p, det_b3, d3out);
    pool_kernel<<<64, blk, 0, stream>>>(d3out, pooled);
    fc_argmax_kernel<<<1, 256, 0, stream>>>(pooled, fc_w, fc_b, pred);

    // ---- gated color-space branch (bf16 hi/lo 3-MFMA; ~fp32 accuracy) ----
    xsplitb_kernel<<<2304, blk, 0, stream>>>(x, pred, xs_hi, xs_lo);
    bconv_kernel<32, 64, 0><<<dim3(2304, BB), blk, 0, stream>>>(
        xs_hi, xs_lo, bw_h1h, bw_h1l, bw_y1h, bw_y1l, hvi_b1, ycc_b1, pred,
        t1_hi, t1_lo, nullptr);
    bconv_kernel<64, 32, 1><<<dim3(2304, BB), blk, 0, stream>>>(
        t1_hi, t1_lo, bw_h2h, bw_h2l, bw_y2h, bw_y2l, hvi_b2, ycc_b2, pred,
        nullptr, nullptr, xb);

    // ---- fused LN + pw(1x1) -> qkvp ----
    lnpw_kernel<<<2304, blk, 0, stream>>>(x, xb, pred, ln_w, ln_b, pw_w, qkvp);

    // ---- q/k dw-on-the-fly + stats; v dw into q-channel slots ----
    qkdwstats_kernel<<<dim3(72, 32), blk, 0, stream>>>(qkvp, dw_w, stats);
    vdw_kernel<<<73728, blk, 0, stream>>>(qkvp, dw_w);
    attnmb_kernel<<<1, 256, 0, stream>>>(stats, temp, proj_w, Mb);

    // ---- epilogue ----
    e1_kernel<<<2304, blk, 0, stream>>>(qkvp, x, xb, pred, Mb, ff1_w);
    fdw_kernel<<<73728, blk, 0, stream>>>(qkvp, ffdw_w, out);
}